// Round 2
// baseline (1710.671 us; speedup 1.0000x reference)
//
#include <hip/hip_runtime.h>
#include <hip/hip_bf16.h>
#include <cstdint>

// Problem constants
#define T_LEN 1024
#define HIDN  1024
#define NH    16
#define DHD   64

typedef __bf16 bf16x8 __attribute__((ext_vector_type(8)));
typedef float  f32x4  __attribute__((ext_vector_type(4)));

// ---------------------------------------------------------------------------
// K1: fp32 -> bf16 hi/lo split (x), vectorized 8/thread
// ---------------------------------------------------------------------------
__global__ __launch_bounds__(256) void k_tobf16_split(const float* __restrict__ in,
                                                      __bf16* __restrict__ hi,
                                                      __bf16* __restrict__ lo, int n8) {
  int i = blockIdx.x * 256 + threadIdx.x;
  if (i >= n8) return;
  const float4* p = (const float4*)in + (size_t)i * 2;
  float4 a = p[0], b = p[1];
  float v[8] = {a.x, a.y, a.z, a.w, b.x, b.y, b.z, b.w};
  union { __bf16 h[8]; uint4 u; } ph, pl;
#pragma unroll
  for (int j = 0; j < 8; j++) {
    __bf16 h = (__bf16)v[j];
    ph.h[j] = h;
    pl.h[j] = (__bf16)(v[j] - (float)h);
  }
  ((uint4*)hi)[i] = ph.u;
  ((uint4*)lo)[i] = pl.u;
}

// ---------------------------------------------------------------------------
// K2: transpose 1024x1024 f32 W[k][n] -> bf16 hi/lo Wt[n][k] (5 weights via z)
// ---------------------------------------------------------------------------
__global__ __launch_bounds__(256) void k_transp_split(
    const float* __restrict__ W0, const float* __restrict__ W1,
    const float* __restrict__ W2, const float* __restrict__ W3,
    const float* __restrict__ W4,
    __bf16* __restrict__ H0, __bf16* __restrict__ H1, __bf16* __restrict__ H2,
    __bf16* __restrict__ H3, __bf16* __restrict__ H4,
    __bf16* __restrict__ L0, __bf16* __restrict__ L1, __bf16* __restrict__ L2,
    __bf16* __restrict__ L3, __bf16* __restrict__ L4) {
  const float* W; __bf16* Th; __bf16* Tl;
  switch (blockIdx.z) {
    case 0: W = W0; Th = H0; Tl = L0; break;
    case 1: W = W1; Th = H1; Tl = L1; break;
    case 2: W = W2; Th = H2; Tl = L2; break;
    case 3: W = W3; Th = H3; Tl = L3; break;
    default: W = W4; Th = H4; Tl = L4; break;
  }
  __shared__ float tile[64][65];
  int tid = threadIdx.x;
  int r0 = tid >> 4;          // 0..15
  int c0 = (tid & 15) * 4;    // 0..60
  int kbase = blockIdx.y * 64, nbase = blockIdx.x * 64;
#pragma unroll
  for (int rr = 0; rr < 4; rr++) {
    int r = r0 + rr * 16;
    float4 v = *(const float4*)(W + (size_t)(kbase + r) * 1024 + nbase + c0);
    tile[r][c0 + 0] = v.x; tile[r][c0 + 1] = v.y;
    tile[r][c0 + 2] = v.z; tile[r][c0 + 3] = v.w;
  }
  __syncthreads();
#pragma unroll
  for (int rr = 0; rr < 4; rr++) {
    int n = r0 + rr * 16;
    union { __bf16 h[4]; unsigned long long u; } ph, pl;
#pragma unroll
    for (int j = 0; j < 4; j++) {
      float v = tile[c0 + j][n];
      __bf16 h = (__bf16)v;
      ph.h[j] = h;
      pl.h[j] = (__bf16)(v - (float)h);
    }
    *(unsigned long long*)(Th + (size_t)(nbase + n) * 1024 + kbase + c0) = ph.u;
    *(unsigned long long*)(Tl + (size_t)(nbase + n) * 1024 + kbase + c0) = pl.u;
  }
}

// ---------------------------------------------------------------------------
// K3: split-precision bf16 MFMA GEMM.
// C[M][1024] f32 = (Ah+Al)[M][K] * (Bh+Bl)[n][k]^T  (3 cross terms, lo*lo dropped)
// 128x128 tile, BK=32, 4 waves (2x2), LDS row stride 40 bf16 (conflict-free)
// ---------------------------------------------------------------------------
#define LDT 40
__global__ __launch_bounds__(256) void k_gemm3(
    const __bf16* __restrict__ Ah, const __bf16* __restrict__ Al,
    const __bf16* __restrict__ Bh0, const __bf16* __restrict__ Bh1,
    const __bf16* __restrict__ Bh2, const __bf16* __restrict__ Bh3,
    const __bf16* __restrict__ Bl0, const __bf16* __restrict__ Bl1,
    const __bf16* __restrict__ Bl2, const __bf16* __restrict__ Bl3,
    float* __restrict__ C0, float* __restrict__ C1,
    float* __restrict__ C2, float* __restrict__ C3,
    int Kdim, int Ncols) {
  const __bf16* Bh; const __bf16* Bl; float* C;
  switch (blockIdx.z) {
    case 0: Bh = Bh0; Bl = Bl0; C = C0; break;
    case 1: Bh = Bh1; Bl = Bl1; C = C1; break;
    case 2: Bh = Bh2; Bl = Bl2; C = C2; break;
    default: Bh = Bh3; Bl = Bl3; C = C3; break;
  }
  __shared__ __bf16 Ash[128 * LDT];
  __shared__ __bf16 Asl[128 * LDT];
  __shared__ __bf16 Bsh[128 * LDT];
  __shared__ __bf16 Bsl[128 * LDT];
  const int tid = threadIdx.x;
  const int lane = tid & 63;
  const int wave = tid >> 6;
  const int wr = wave >> 1, wc = wave & 1;
  const int rowA0 = blockIdx.y * 128;
  const int colB0 = blockIdx.x * 128;
  const int sseg = tid & 3;       // 16B segment within 64B row
  const int srow0 = tid >> 2;     // 0..63
  const int srow1 = srow0 + 64;   // 64..127

  f32x4 acc[4][4] = {};

  for (int k0 = 0; k0 < Kdim; k0 += 32) {
    size_t a0 = (size_t)(rowA0 + srow0) * Kdim + k0 + sseg * 8;
    size_t a1 = (size_t)(rowA0 + srow1) * Kdim + k0 + sseg * 8;
    size_t b0 = (size_t)(colB0 + srow0) * Kdim + k0 + sseg * 8;
    size_t b1 = (size_t)(colB0 + srow1) * Kdim + k0 + sseg * 8;
    uint4 rah0 = *(const uint4*)(Ah + a0);
    uint4 rah1 = *(const uint4*)(Ah + a1);
    uint4 ral0 = *(const uint4*)(Al + a0);
    uint4 ral1 = *(const uint4*)(Al + a1);
    uint4 rbh0 = *(const uint4*)(Bh + b0);
    uint4 rbh1 = *(const uint4*)(Bh + b1);
    uint4 rbl0 = *(const uint4*)(Bl + b0);
    uint4 rbl1 = *(const uint4*)(Bl + b1);
    __syncthreads();
    *(uint4*)&Ash[srow0 * LDT + sseg * 8] = rah0;
    *(uint4*)&Ash[srow1 * LDT + sseg * 8] = rah1;
    *(uint4*)&Asl[srow0 * LDT + sseg * 8] = ral0;
    *(uint4*)&Asl[srow1 * LDT + sseg * 8] = ral1;
    *(uint4*)&Bsh[srow0 * LDT + sseg * 8] = rbh0;
    *(uint4*)&Bsh[srow1 * LDT + sseg * 8] = rbh1;
    *(uint4*)&Bsl[srow0 * LDT + sseg * 8] = rbl0;
    *(uint4*)&Bsl[srow1 * LDT + sseg * 8] = rbl1;
    __syncthreads();
    bf16x8 afh[4], afl[4], bfh[4], bfl[4];
#pragma unroll
    for (int mi = 0; mi < 4; mi++) {
      int off = (wr * 64 + mi * 16 + (lane & 15)) * LDT + (lane >> 4) * 8;
      afh[mi] = *(const bf16x8*)&Ash[off];
      afl[mi] = *(const bf16x8*)&Asl[off];
    }
#pragma unroll
    for (int ni = 0; ni < 4; ni++) {
      int off = (wc * 64 + ni * 16 + (lane & 15)) * LDT + (lane >> 4) * 8;
      bfh[ni] = *(const bf16x8*)&Bsh[off];
      bfl[ni] = *(const bf16x8*)&Bsl[off];
    }
#pragma unroll
    for (int mi = 0; mi < 4; mi++)
#pragma unroll
      for (int ni = 0; ni < 4; ni++) {
        acc[mi][ni] = __builtin_amdgcn_mfma_f32_16x16x32_bf16(afh[mi], bfh[ni], acc[mi][ni], 0, 0, 0);
        acc[mi][ni] = __builtin_amdgcn_mfma_f32_16x16x32_bf16(afl[mi], bfh[ni], acc[mi][ni], 0, 0, 0);
        acc[mi][ni] = __builtin_amdgcn_mfma_f32_16x16x32_bf16(afh[mi], bfl[ni], acc[mi][ni], 0, 0, 0);
      }
  }
#pragma unroll
  for (int mi = 0; mi < 4; mi++)
#pragma unroll
    for (int ni = 0; ni < 4; ni++) {
      int col = colB0 + wc * 64 + ni * 16 + (lane & 15);
#pragma unroll
      for (int r = 0; r < 4; r++) {
        int row = rowA0 + wr * 64 + mi * 16 + (lane >> 4) * 4 + r;
        C[(size_t)row * Ncols + col] = acc[mi][ni][r];
      }
    }
}

// ---------------------------------------------------------------------------
// K4: gates: beta = sigmoid(x@bw+bb), alpha = exp(-exp(A_log)*softplus(x@gkw+gkb+dt_bias))
// ---------------------------------------------------------------------------
__global__ __launch_bounds__(256) void k_gates(
    const float* __restrict__ x, const float* __restrict__ bw,
    const float* __restrict__ bb, const float* __restrict__ gkw,
    const float* __restrict__ gkb, const float* __restrict__ A_log,
    const float* __restrict__ dt_bias,
    float* __restrict__ alphaB, float* __restrict__ betaB) {
  const int bt = blockIdx.x;
  const int tid = threadIdx.x;
  const int h = tid & 15;
  const int chunk = tid >> 4;
  const float* xr = x + (size_t)bt * HIDN;
  float d1 = 0.f, d2 = 0.f;
#pragma unroll 8
  for (int j = 0; j < 64; j++) {
    int k = chunk * 64 + j;
    float xv = xr[k];
    d1 += xv * bw[k * 16 + h];
    d2 += xv * gkw[k * 16 + h];
  }
  __shared__ float p1[16][16], p2[16][16];
  p1[chunk][h] = d1; p2[chunk][h] = d2;
  __syncthreads();
  if (tid < 16) {
    float s1 = 0.f, s2 = 0.f;
#pragma unroll
    for (int c = 0; c < 16; c++) { s1 += p1[c][tid]; s2 += p2[c][tid]; }
    float beta = 1.f / (1.f + expf(-(s1 + bb[tid])));
    float z = s2 + gkb[tid] + dt_bias[tid];
    float sp = fmaxf(z, 0.f) + log1pf(expf(-fabsf(z)));
    float alpha = expf(-expf(A_log[tid]) * sp);
    alphaB[(size_t)bt * 16 + tid] = alpha;
    betaB[(size_t)bt * 16 + tid] = beta;
  }
}

// ---------------------------------------------------------------------------
// K5: rope tables ct/st[t][i], i=0..31, angle = t * 10000^(-2*(i&15)/32)
// ---------------------------------------------------------------------------
__global__ __launch_bounds__(256) void k_rope_table(float* __restrict__ ct,
                                                    float* __restrict__ st) {
  int idx = blockIdx.x * 256 + threadIdx.x;
  if (idx >= T_LEN * 32) return;
  int t = idx >> 5, i = idx & 31;
  int m = 2 * (i & 15);
  float f = expf(-(float)m * (9.210340371976184f / 32.f));  // ln(10000)/32
  float ang = (float)t * f;
  ct[idx] = cosf(ang);
  st[idx] = sinf(ang);
}

// ---------------------------------------------------------------------------
// K6: causal depthwise conv (K=4) + bias + SiLU for q,k,v (3 tensors via y)
// v is written directly in scan layout [b][h][t][d]
// ---------------------------------------------------------------------------
__global__ __launch_bounds__(256) void k_conv(
    const float* __restrict__ in0, const float* __restrict__ in1,
    const float* __restrict__ in2,
    const float* __restrict__ w0, const float* __restrict__ w1,
    const float* __restrict__ w2,
    const float* __restrict__ b0, const float* __restrict__ b1,
    const float* __restrict__ b2,
    float* __restrict__ o0, float* __restrict__ o1, float* __restrict__ o2) {
  const int tensor = blockIdx.y;
  const float* in; const float* w; const float* bias; float* out;
  switch (tensor) {
    case 0: in = in0; w = w0; bias = b0; out = o0; break;
    case 1: in = in1; w = w1; bias = b1; out = o1; break;
    default: in = in2; w = w2; bias = b2; out = o2; break;
  }
  int idx = blockIdx.x * 256 + threadIdx.x;  // [0, 2M)
  int c = idx & 1023;
  int bt = idx >> 10;
  int t = bt & 1023, b = bt >> 10;
  float4 wc4 = *(const float4*)(w + (size_t)c * 4);
  const float* col = in + ((size_t)b * 1024) * 1024 + c;
  float xm3 = (t >= 3) ? col[(size_t)(t - 3) * 1024] : 0.f;
  float xm2 = (t >= 2) ? col[(size_t)(t - 2) * 1024] : 0.f;
  float xm1 = (t >= 1) ? col[(size_t)(t - 1) * 1024] : 0.f;
  float x0 = col[(size_t)t * 1024];
  float acc = bias[c] + wc4.x * xm3 + wc4.y * xm2 + wc4.z * xm1 + wc4.w * x0;
  float y = acc / (1.f + expf(-acc));
  if (tensor < 2) {
    out[(size_t)bt * 1024 + c] = y;
  } else {
    int h = c >> 6, d = c & 63;
    out[(((size_t)(b * 16 + h)) * 1024 + t) * 64 + d] = y;
  }
}

// ---------------------------------------------------------------------------
// K7: RoPE + L2-norm for q,k  (one wave per (b,t,h)); also packs aux
//   aux[bh][t] = {alpha, beta, alpha*beta, D[h]*dot(qn,kn)}
// ---------------------------------------------------------------------------
__global__ __launch_bounds__(256) void k_ropenorm(
    const float* __restrict__ qc, const float* __restrict__ kc,
    const float* __restrict__ ct, const float* __restrict__ st,
    const float* __restrict__ alphaB, const float* __restrict__ betaB,
    const float* __restrict__ Dp,
    float* __restrict__ qr, float* __restrict__ kr, float4* __restrict__ aux) {
  int widx = blockIdx.x * 4 + (threadIdx.x >> 6);
  int lane = threadIdx.x & 63;
  int h = widx & 15;
  int bt = widx >> 4;
  int t = bt & 1023, b = bt >> 10;
  const float* qrow = qc + (size_t)bt * 1024 + h * 64;
  const float* krow = kc + (size_t)bt * 1024 + h * 64;
  int i = lane & 31;
  float cv = ct[t * 32 + i], sv = st[t * 32 + i];
  float q1 = qrow[2 * i], q2 = qrow[2 * i + 1];
  float k1 = krow[2 * i], k2 = krow[2 * i + 1];
  float qo = (lane < 32) ? (q1 * cv - q2 * sv) : (q1 * sv + q2 * cv);
  float ko = (lane < 32) ? (k1 * cv - k2 * sv) : (k1 * sv + k2 * cv);
  float qs = qo * qo, ks2 = ko * ko;
#pragma unroll
  for (int m = 1; m < 64; m <<= 1) { qs += __shfl_xor(qs, m); ks2 += __shfl_xor(ks2, m); }
  float qn = qo * rsqrtf(qs + 1e-6f);
  float kn = ko * rsqrtf(ks2 + 1e-6f);
  float dq = qn * kn;
#pragma unroll
  for (int m = 1; m < 64; m <<= 1) dq += __shfl_xor(dq, m);
  size_t obase = ((size_t)(b * 16 + h) * 1024 + t) * 64;
  qr[obase + lane] = qn;
  kr[obase + lane] = kn;
  if (lane == 0) {
    float alpha = alphaB[(size_t)bt * 16 + h];
    float beta = betaB[(size_t)bt * 16 + h];
    aux[(size_t)(b * 16 + h) * 1024 + t] = make_float4(alpha, beta, alpha * beta, Dp[h] * dq);
  }
}

// ---------------------------------------------------------------------------
// K8: sequential delta-rule scan. 1 wave per (b,h); lane = value-dim e.
// ---------------------------------------------------------------------------
__global__ __launch_bounds__(64) void k_scan(
    const float* __restrict__ qr, const float* __restrict__ kr,
    const float* __restrict__ vr, const float* __restrict__ aux,
    float* __restrict__ obuf) {
  const int bh = blockIdx.x;
  const int lane = threadIdx.x;
  const float* qB = qr + (size_t)bh * T_LEN * DHD;
  const float* kB = kr + (size_t)bh * T_LEN * DHD;
  const float* vB = vr + (size_t)bh * T_LEN * DHD;
  const float4* auxB = (const float4*)aux + (size_t)bh * T_LEN;
  float* oB = obuf + (size_t)bh * T_LEN * DHD;

  __shared__ float qs[16 * 64], ks[16 * 64], vs[16 * 64];
  __shared__ float4 as_[16];

  float S[64];
#pragma unroll
  for (int i = 0; i < 64; i++) S[i] = 0.f;

  for (int t0 = 0; t0 < T_LEN; t0 += 16) {
#pragma unroll
    for (int r = 0; r < 4; r++) {
      int off = r * 256 + lane * 4;
      *(float4*)&qs[off] = *(const float4*)(qB + (size_t)t0 * 64 + off);
      *(float4*)&ks[off] = *(const float4*)(kB + (size_t)t0 * 64 + off);
      *(float4*)&vs[off] = *(const float4*)(vB + (size_t)t0 * 64 + off);
    }
    if (lane < 16) as_[lane] = auxB[t0 + lane];
    __syncthreads();
    for (int tt = 0; tt < 16; ++tt) {
      float4 qreg[16], kreg[16];
#pragma unroll
      for (int j = 0; j < 16; j++) {
        qreg[j] = *(const float4*)&qs[tt * 64 + j * 4];  // uniform addr -> broadcast
        kreg[j] = *(const float4*)&ks[tt * 64 + j * 4];
      }
      float o0 = 0, o1 = 0, o2 = 0, o3 = 0, z0 = 0, z1 = 0, z2 = 0, z3 = 0;
#pragma unroll
      for (int j = 0; j < 16; j++) {
        o0 += qreg[j].x * S[4 * j + 0]; z0 += kreg[j].x * S[4 * j + 0];
        o1 += qreg[j].y * S[4 * j + 1]; z1 += kreg[j].y * S[4 * j + 1];
        o2 += qreg[j].z * S[4 * j + 2]; z2 += kreg[j].z * S[4 * j + 2];
        o3 += qreg[j].w * S[4 * j + 3]; z3 += kreg[j].w * S[4 * j + 3];
      }
      float oS = (o0 + o1) + (o2 + o3);
      float kz = (z0 + z1) + (z2 + z3);
      float4 a4 = as_[tt];
      float vv = vs[tt * 64 + lane];
      float cc = a4.y * vv - a4.z * kz;  // beta*v - (alpha*beta)*kS
      oB[(size_t)(t0 + tt) * 64 + lane] = oS + a4.w * vv;
      float al = a4.x;
#pragma unroll
      for (int j = 0; j < 16; j++) {
        S[4 * j + 0] = al * S[4 * j + 0] + kreg[j].x * cc;
        S[4 * j + 1] = al * S[4 * j + 1] + kreg[j].y * cc;
        S[4 * j + 2] = al * S[4 * j + 2] + kreg[j].z * cc;
        S[4 * j + 3] = al * S[4 * j + 3] + kreg[j].w * cc;
      }
    }
    __syncthreads();
  }
}

// ---------------------------------------------------------------------------
// K9: output RMS-norm + gate, writes bf16 hi/lo pair in [bt][h*64+d] layout
// ---------------------------------------------------------------------------
__global__ __launch_bounds__(256) void k_outnorm(
    const float* __restrict__ obuf, const float* __restrict__ g,
    const float* __restrict__ onw, __bf16* __restrict__ rh,
    __bf16* __restrict__ rl) {
  int widx = blockIdx.x * 4 + (threadIdx.x >> 6);
  int lane = threadIdx.x & 63;
  int h = widx & 15, bt = widx >> 4;
  int t = bt & 1023, b = bt >> 10;
  float ov = obuf[(((size_t)(b * 16 + h)) * 1024 + t) * 64 + lane];
  float ss = ov * ov;
#pragma unroll
  for (int m = 1; m < 64; m <<= 1) ss += __shfl_xor(ss, m);
  float on = ov * rsqrtf(ss * (1.f / 64.f) + 1e-6f) * onw[lane];
  float sil = on / (1.f + expf(-on));
  float gv = g[(size_t)bt * 1024 + h * 64 + lane];
  float r = gv * sil;
  __bf16 hv = (__bf16)r;
  rh[(size_t)bt * 1024 + h * 64 + lane] = hv;
  rl[(size_t)bt * 1024 + h * 64 + lane] = (__bf16)(r - (float)hv);
}

// ---------------------------------------------------------------------------
extern "C" void kernel_launch(void* const* d_in, const int* in_sizes, int n_in,
                              void* d_out, int out_size, void* d_ws, size_t ws_size,
                              hipStream_t stream) {
  (void)in_sizes; (void)n_in; (void)out_size; (void)ws_size;
  const float* x    = (const float*)d_in[0];
  const float* Wq   = (const float*)d_in[1];
  const float* Wk   = (const float*)d_in[2];
  const float* Wv   = (const float*)d_in[3];
  const float* Wg   = (const float*)d_in[4];
  const float* Wo   = (const float*)d_in[5];
  const float* bw   = (const float*)d_in[6];
  const float* bb   = (const float*)d_in[7];
  const float* gkw  = (const float*)d_in[8];
  const float* gkb  = (const float*)d_in[9];
  const float* qcw  = (const float*)d_in[10];
  const float* qcb  = (const float*)d_in[11];
  const float* kcw  = (const float*)d_in[12];
  const float* kcb  = (const float*)d_in[13];
  const float* vcw  = (const float*)d_in[14];
  const float* vcb  = (const float*)d_in[15];
  const float* A_log= (const float*)d_in[16];
  const float* Dp   = (const float*)d_in[17];
  const float* dtb  = (const float*)d_in[18];
  const float* onw  = (const float*)d_in[19];

  char* ws = (char*)d_ws;
  const size_t MB = 1024 * 1024;
  // region 0..8MB: xb hi/lo  (dead after projections) -> reused: qc (conv q out, 8MB) -> reused: r hi/lo
  __bf16* xb_h = (__bf16*)(ws + 0);
  __bf16* xb_l = (__bf16*)(ws + 4 * MB);
  // region 8..24MB: Wq/Wk/Wv/Wg hi+lo (dead after projections) -> reused: kc (8..16), vr (16..24)
  __bf16* Wq_h = (__bf16*)(ws + 8 * MB);
  __bf16* Wq_l = (__bf16*)(ws + 10 * MB);
  __bf16* Wk_h = (__bf16*)(ws + 12 * MB);
  __bf16* Wk_l = (__bf16*)(ws + 14 * MB);
  __bf16* Wv_h = (__bf16*)(ws + 16 * MB);
  __bf16* Wv_l = (__bf16*)(ws + 18 * MB);
  __bf16* Wg_h = (__bf16*)(ws + 20 * MB);
  __bf16* Wg_l = (__bf16*)(ws + 22 * MB);
  // region 24..28MB: Wo hi/lo (live until end)
  __bf16* Wo_h = (__bf16*)(ws + 24 * MB);
  __bf16* Wo_l = (__bf16*)(ws + 26 * MB);
  // fp32 intermediates
  float* q_pre = (float*)(ws + 28 * MB);   // -> qrb
  float* k_pre = (float*)(ws + 36 * MB);   // -> krb
  float* v_pre = (float*)(ws + 44 * MB);   // -> obuf
  float* g_buf = (float*)(ws + 52 * MB);
  float* qc    = (float*)(ws + 0);         // alias xb region (dead after gemm)
  float* kc    = (float*)(ws + 8 * MB);    // alias Wq region
  float* vr    = (float*)(ws + 16 * MB);   // alias Wv region
  float* qrb   = q_pre;                    // ropenorm out (q_pre dead after conv)
  float* krb   = k_pre;
  float* obuf  = v_pre;                    // scan out (v_pre dead after conv... after scan input read)
  __bf16* r_h  = (__bf16*)(ws + 0);        // alias qc (dead after ropenorm)
  __bf16* r_l  = (__bf16*)(ws + 4 * MB);
  // small buffers at 60MB
  float* alphaB = (float*)(ws + 60 * MB);
  float* betaB  = (float*)(ws + 60 * MB + 128 * 1024);
  float4* aux   = (float4*)(ws + 60 * MB + 256 * 1024);
  float* ct     = (float*)(ws + 60 * MB + 768 * 1024);
  float* st     = (float*)(ws + 60 * MB + 896 * 1024);
  float* out    = (float*)d_out;

  // independent preprocessing
  k_tobf16_split<<<1024, 256, 0, stream>>>(x, xb_h, xb_l, 262144);
  k_transp_split<<<dim3(16, 16, 5), 256, 0, stream>>>(
      Wq, Wk, Wv, Wg, Wo,
      Wq_h, Wk_h, Wv_h, Wg_h, Wo_h,
      Wq_l, Wk_l, Wv_l, Wg_l, Wo_l);
  k_rope_table<<<128, 256, 0, stream>>>(ct, st);
  k_gates<<<2048, 256, 0, stream>>>(x, bw, bb, gkw, gkb, A_log, dtb, alphaB, betaB);
  // projections (split precision)
  k_gemm3<<<dim3(8, 16, 4), 256, 0, stream>>>(
      xb_h, xb_l,
      Wq_h, Wk_h, Wv_h, Wg_h,
      Wq_l, Wk_l, Wv_l, Wg_l,
      q_pre, k_pre, v_pre, g_buf, 1024, 1024);
  // conv + silu
  k_conv<<<dim3(8192, 3), 256, 0, stream>>>(q_pre, k_pre, v_pre, qcw, kcw, vcw,
                                            qcb, kcb, vcb, qc, kc, vr);
  // rope + l2 norm + aux pack
  k_ropenorm<<<8192, 256, 0, stream>>>(qc, kc, ct, st, alphaB, betaB, Dp, qrb, krb, aux);
  // sequential delta rule
  k_scan<<<32, 64, 0, stream>>>(qrb, krb, vr, (const float*)aux, obuf);
  // output norm + gate (split bf16)
  k_outnorm<<<8192, 256, 0, stream>>>(obuf, g_buf, onw, r_h, r_l);
  // final projection (split precision)
  k_gemm3<<<dim3(8, 16, 1), 256, 0, stream>>>(
      r_h, r_l,
      Wo_h, Wo_h, Wo_h, Wo_h,
      Wo_l, Wo_l, Wo_l, Wo_l,
      out, out, out, out, 1024, 1024);
}

// Round 4
// 784.494 us; speedup vs baseline: 2.1806x; 2.1806x over previous
//
#include <hip/hip_runtime.h>
#include <hip/hip_bf16.h>
#include <cstdint>

// Problem constants
#define T_LEN 1024
#define HIDN  1024
#define NH    16
#define DHD   64

typedef __bf16 bf16x8 __attribute__((ext_vector_type(8)));
typedef float  f32x4  __attribute__((ext_vector_type(4)));

// ---------------------------------------------------------------------------
// K1: fp32 -> bf16 hi/lo split (x), vectorized 8/thread
// ---------------------------------------------------------------------------
__global__ __launch_bounds__(256) void k_tobf16_split(const float* __restrict__ in,
                                                      __bf16* __restrict__ hi,
                                                      __bf16* __restrict__ lo, int n8) {
  int i = blockIdx.x * 256 + threadIdx.x;
  if (i >= n8) return;
  const float4* p = (const float4*)in + (size_t)i * 2;
  float4 a = p[0], b = p[1];
  float v[8] = {a.x, a.y, a.z, a.w, b.x, b.y, b.z, b.w};
  union { __bf16 h[8]; uint4 u; } ph, pl;
#pragma unroll
  for (int j = 0; j < 8; j++) {
    __bf16 h = (__bf16)v[j];
    ph.h[j] = h;
    pl.h[j] = (__bf16)(v[j] - (float)h);
  }
  ((uint4*)hi)[i] = ph.u;
  ((uint4*)lo)[i] = pl.u;
}

// ---------------------------------------------------------------------------
// K2: transpose 1024x1024 f32 W[k][n] -> bf16 hi/lo Wt[n][k] (5 weights via z)
// ---------------------------------------------------------------------------
__global__ __launch_bounds__(256) void k_transp_split(
    const float* __restrict__ W0, const float* __restrict__ W1,
    const float* __restrict__ W2, const float* __restrict__ W3,
    const float* __restrict__ W4,
    __bf16* __restrict__ H0, __bf16* __restrict__ H1, __bf16* __restrict__ H2,
    __bf16* __restrict__ H3, __bf16* __restrict__ H4,
    __bf16* __restrict__ L0, __bf16* __restrict__ L1, __bf16* __restrict__ L2,
    __bf16* __restrict__ L3, __bf16* __restrict__ L4) {
  const float* W; __bf16* Th; __bf16* Tl;
  switch (blockIdx.z) {
    case 0: W = W0; Th = H0; Tl = L0; break;
    case 1: W = W1; Th = H1; Tl = L1; break;
    case 2: W = W2; Th = H2; Tl = L2; break;
    case 3: W = W3; Th = H3; Tl = L3; break;
    default: W = W4; Th = H4; Tl = L4; break;
  }
  __shared__ float tile[64][65];
  int tid = threadIdx.x;
  int r0 = tid >> 4;          // 0..15
  int c0 = (tid & 15) * 4;    // 0..60
  int kbase = blockIdx.y * 64, nbase = blockIdx.x * 64;
#pragma unroll
  for (int rr = 0; rr < 4; rr++) {
    int r = r0 + rr * 16;
    float4 v = *(const float4*)(W + (size_t)(kbase + r) * 1024 + nbase + c0);
    tile[r][c0 + 0] = v.x; tile[r][c0 + 1] = v.y;
    tile[r][c0 + 2] = v.z; tile[r][c0 + 3] = v.w;
  }
  __syncthreads();
#pragma unroll
  for (int rr = 0; rr < 4; rr++) {
    int n = r0 + rr * 16;
    union { __bf16 h[4]; unsigned long long u; } ph, pl;
#pragma unroll
    for (int j = 0; j < 4; j++) {
      float v = tile[c0 + j][n];
      __bf16 h = (__bf16)v;
      ph.h[j] = h;
      pl.h[j] = (__bf16)(v - (float)h);
    }
    *(unsigned long long*)(Th + (size_t)(nbase + n) * 1024 + kbase + c0) = ph.u;
    *(unsigned long long*)(Tl + (size_t)(nbase + n) * 1024 + kbase + c0) = pl.u;
  }
}

// ---------------------------------------------------------------------------
// K3: split-precision bf16 MFMA GEMM (3 cross terms, lo*lo dropped)
// ---------------------------------------------------------------------------
#define LDT 40
__global__ __launch_bounds__(256) void k_gemm3(
    const __bf16* __restrict__ Ah, const __bf16* __restrict__ Al,
    const __bf16* __restrict__ Bh0, const __bf16* __restrict__ Bh1,
    const __bf16* __restrict__ Bh2, const __bf16* __restrict__ Bh3,
    const __bf16* __restrict__ Bl0, const __bf16* __restrict__ Bl1,
    const __bf16* __restrict__ Bl2, const __bf16* __restrict__ Bl3,
    float* __restrict__ C0, float* __restrict__ C1,
    float* __restrict__ C2, float* __restrict__ C3,
    int Kdim, int Ncols) {
  const __bf16* Bh; const __bf16* Bl; float* C;
  switch (blockIdx.z) {
    case 0: Bh = Bh0; Bl = Bl0; C = C0; break;
    case 1: Bh = Bh1; Bl = Bl1; C = C1; break;
    case 2: Bh = Bh2; Bl = Bl2; C = C2; break;
    default: Bh = Bh3; Bl = Bl3; C = C3; break;
  }
  __shared__ __bf16 Ash[128 * LDT];
  __shared__ __bf16 Asl[128 * LDT];
  __shared__ __bf16 Bsh[128 * LDT];
  __shared__ __bf16 Bsl[128 * LDT];
  const int tid = threadIdx.x;
  const int lane = tid & 63;
  const int wave = tid >> 6;
  const int wr = wave >> 1, wc = wave & 1;
  const int rowA0 = blockIdx.y * 128;
  const int colB0 = blockIdx.x * 128;
  const int sseg = tid & 3;
  const int srow0 = tid >> 2;
  const int srow1 = srow0 + 64;

  f32x4 acc[4][4] = {};

  for (int k0 = 0; k0 < Kdim; k0 += 32) {
    size_t a0 = (size_t)(rowA0 + srow0) * Kdim + k0 + sseg * 8;
    size_t a1 = (size_t)(rowA0 + srow1) * Kdim + k0 + sseg * 8;
    size_t b0 = (size_t)(colB0 + srow0) * Kdim + k0 + sseg * 8;
    size_t b1 = (size_t)(colB0 + srow1) * Kdim + k0 + sseg * 8;
    uint4 rah0 = *(const uint4*)(Ah + a0);
    uint4 rah1 = *(const uint4*)(Ah + a1);
    uint4 ral0 = *(const uint4*)(Al + a0);
    uint4 ral1 = *(const uint4*)(Al + a1);
    uint4 rbh0 = *(const uint4*)(Bh + b0);
    uint4 rbh1 = *(const uint4*)(Bh + b1);
    uint4 rbl0 = *(const uint4*)(Bl + b0);
    uint4 rbl1 = *(const uint4*)(Bl + b1);
    __syncthreads();
    *(uint4*)&Ash[srow0 * LDT + sseg * 8] = rah0;
    *(uint4*)&Ash[srow1 * LDT + sseg * 8] = rah1;
    *(uint4*)&Asl[srow0 * LDT + sseg * 8] = ral0;
    *(uint4*)&Asl[srow1 * LDT + sseg * 8] = ral1;
    *(uint4*)&Bsh[srow0 * LDT + sseg * 8] = rbh0;
    *(uint4*)&Bsh[srow1 * LDT + sseg * 8] = rbh1;
    *(uint4*)&Bsl[srow0 * LDT + sseg * 8] = rbl0;
    *(uint4*)&Bsl[srow1 * LDT + sseg * 8] = rbl1;
    __syncthreads();
    bf16x8 afh[4], afl[4], bfh[4], bfl[4];
#pragma unroll
    for (int mi = 0; mi < 4; mi++) {
      int off = (wr * 64 + mi * 16 + (lane & 15)) * LDT + (lane >> 4) * 8;
      afh[mi] = *(const bf16x8*)&Ash[off];
      afl[mi] = *(const bf16x8*)&Asl[off];
    }
#pragma unroll
    for (int ni = 0; ni < 4; ni++) {
      int off = (wc * 64 + ni * 16 + (lane & 15)) * LDT + (lane >> 4) * 8;
      bfh[ni] = *(const bf16x8*)&Bsh[off];
      bfl[ni] = *(const bf16x8*)&Bsl[off];
    }
#pragma unroll
    for (int mi = 0; mi < 4; mi++)
#pragma unroll
      for (int ni = 0; ni < 4; ni++) {
        acc[mi][ni] = __builtin_amdgcn_mfma_f32_16x16x32_bf16(afh[mi], bfh[ni], acc[mi][ni], 0, 0, 0);
        acc[mi][ni] = __builtin_amdgcn_mfma_f32_16x16x32_bf16(afl[mi], bfh[ni], acc[mi][ni], 0, 0, 0);
        acc[mi][ni] = __builtin_amdgcn_mfma_f32_16x16x32_bf16(afh[mi], bfl[ni], acc[mi][ni], 0, 0, 0);
      }
  }
#pragma unroll
  for (int mi = 0; mi < 4; mi++)
#pragma unroll
    for (int ni = 0; ni < 4; ni++) {
      int col = colB0 + wc * 64 + ni * 16 + (lane & 15);
#pragma unroll
      for (int r = 0; r < 4; r++) {
        int row = rowA0 + wr * 64 + mi * 16 + (lane >> 4) * 4 + r;
        C[(size_t)row * Ncols + col] = acc[mi][ni][r];
      }
    }
}

// ---------------------------------------------------------------------------
// K4: gates
// ---------------------------------------------------------------------------
__global__ __launch_bounds__(256) void k_gates(
    const float* __restrict__ x, const float* __restrict__ bw,
    const float* __restrict__ bb, const float* __restrict__ gkw,
    const float* __restrict__ gkb, const float* __restrict__ A_log,
    const float* __restrict__ dt_bias,
    float* __restrict__ alphaB, float* __restrict__ betaB) {
  const int bt = blockIdx.x;
  const int tid = threadIdx.x;
  const int h = tid & 15;
  const int chunk = tid >> 4;
  const float* xr = x + (size_t)bt * HIDN;
  float d1 = 0.f, d2 = 0.f;
#pragma unroll 8
  for (int j = 0; j < 64; j++) {
    int k = chunk * 64 + j;
    float xv = xr[k];
    d1 += xv * bw[k * 16 + h];
    d2 += xv * gkw[k * 16 + h];
  }
  __shared__ float p1[16][16], p2[16][16];
  p1[chunk][h] = d1; p2[chunk][h] = d2;
  __syncthreads();
  if (tid < 16) {
    float s1 = 0.f, s2 = 0.f;
#pragma unroll
    for (int c = 0; c < 16; c++) { s1 += p1[c][tid]; s2 += p2[c][tid]; }
    float beta = 1.f / (1.f + expf(-(s1 + bb[tid])));
    float z = s2 + gkb[tid] + dt_bias[tid];
    float sp = fmaxf(z, 0.f) + log1pf(expf(-fabsf(z)));
    float alpha = expf(-expf(A_log[tid]) * sp);
    alphaB[(size_t)bt * 16 + tid] = alpha;
    betaB[(size_t)bt * 16 + tid] = beta;
  }
}

// ---------------------------------------------------------------------------
// K5: rope tables
// ---------------------------------------------------------------------------
__global__ __launch_bounds__(256) void k_rope_table(float* __restrict__ ct,
                                                    float* __restrict__ st) {
  int idx = blockIdx.x * 256 + threadIdx.x;
  if (idx >= T_LEN * 32) return;
  int t = idx >> 5, i = idx & 31;
  int m = 2 * (i & 15);
  float f = expf(-(float)m * (9.210340371976184f / 32.f));
  float ang = (float)t * f;
  ct[idx] = cosf(ang);
  st[idx] = sinf(ang);
}

// ---------------------------------------------------------------------------
// K6: causal depthwise conv (K=4) + bias + SiLU
// ---------------------------------------------------------------------------
__global__ __launch_bounds__(256) void k_conv(
    const float* __restrict__ in0, const float* __restrict__ in1,
    const float* __restrict__ in2,
    const float* __restrict__ w0, const float* __restrict__ w1,
    const float* __restrict__ w2,
    const float* __restrict__ b0, const float* __restrict__ b1,
    const float* __restrict__ b2,
    float* __restrict__ o0, float* __restrict__ o1, float* __restrict__ o2) {
  const int tensor = blockIdx.y;
  const float* in; const float* w; const float* bias; float* out;
  switch (tensor) {
    case 0: in = in0; w = w0; bias = b0; out = o0; break;
    case 1: in = in1; w = w1; bias = b1; out = o1; break;
    default: in = in2; w = w2; bias = b2; out = o2; break;
  }
  int idx = blockIdx.x * 256 + threadIdx.x;
  int c = idx & 1023;
  int bt = idx >> 10;
  int t = bt & 1023, b = bt >> 10;
  float4 wc4 = *(const float4*)(w + (size_t)c * 4);
  const float* col = in + ((size_t)b * 1024) * 1024 + c;
  float xm3 = (t >= 3) ? col[(size_t)(t - 3) * 1024] : 0.f;
  float xm2 = (t >= 2) ? col[(size_t)(t - 2) * 1024] : 0.f;
  float xm1 = (t >= 1) ? col[(size_t)(t - 1) * 1024] : 0.f;
  float x0 = col[(size_t)t * 1024];
  float acc = bias[c] + wc4.x * xm3 + wc4.y * xm2 + wc4.z * xm1 + wc4.w * x0;
  float y = acc / (1.f + expf(-acc));
  if (tensor < 2) {
    out[(size_t)bt * 1024 + c] = y;
  } else {
    int h = c >> 6, d = c & 63;
    out[(((size_t)(b * 16 + h)) * 1024 + t) * 64 + d] = y;
  }
}

// ---------------------------------------------------------------------------
// K7: RoPE + L2-norm for q,k; packs aux = {alpha, beta, alpha*beta, D*(q.k)}
// ---------------------------------------------------------------------------
__global__ __launch_bounds__(256) void k_ropenorm(
    const float* __restrict__ qc, const float* __restrict__ kc,
    const float* __restrict__ ct, const float* __restrict__ st,
    const float* __restrict__ alphaB, const float* __restrict__ betaB,
    const float* __restrict__ Dp,
    float* __restrict__ qr, float* __restrict__ kr, float4* __restrict__ aux) {
  int widx = blockIdx.x * 4 + (threadIdx.x >> 6);
  int lane = threadIdx.x & 63;
  int h = widx & 15;
  int bt = widx >> 4;
  int t = bt & 1023, b = bt >> 10;
  const float* qrow = qc + (size_t)bt * 1024 + h * 64;
  const float* krow = kc + (size_t)bt * 1024 + h * 64;
  int i = lane & 31;
  float cv = ct[t * 32 + i], sv = st[t * 32 + i];
  float q1 = qrow[2 * i], q2 = qrow[2 * i + 1];
  float k1 = krow[2 * i], k2 = krow[2 * i + 1];
  float qo = (lane < 32) ? (q1 * cv - q2 * sv) : (q1 * sv + q2 * cv);
  float ko = (lane < 32) ? (k1 * cv - k2 * sv) : (k1 * sv + k2 * cv);
  float qs = qo * qo, ks2 = ko * ko;
#pragma unroll
  for (int m = 1; m < 64; m <<= 1) { qs += __shfl_xor(qs, m); ks2 += __shfl_xor(ks2, m); }
  float qn = qo * rsqrtf(qs + 1e-6f);
  float kn = ko * rsqrtf(ks2 + 1e-6f);
  float dq = qn * kn;
#pragma unroll
  for (int m = 1; m < 64; m <<= 1) dq += __shfl_xor(dq, m);
  size_t obase = ((size_t)(b * 16 + h) * 1024 + t) * 64;
  qr[obase + lane] = qn;
  kr[obase + lane] = kn;
  if (lane == 0) {
    float alpha = alphaB[(size_t)bt * 16 + h];
    float beta = betaB[(size_t)bt * 16 + h];
    aux[(size_t)(b * 16 + h) * 1024 + t] = make_float4(alpha, beta, alpha * beta, Dp[h] * dq);
  }
}

// ---------------------------------------------------------------------------
// K8: chunked WY-form delta-rule scan. 1 wave per (b,h), 16 chunks of 64.
//
// Per chunk (0-based step j, cumulative decay lg[j] = sum_{i<=j} log(alpha_i)):
//   KK = K K^T, QK = Q K^T, KS0 = K @ S0, QS0 = Q @ S0    (MFMA, bf16)
//   MT[j][r] = (r>j) ? beta_r * exp(lg[r]-lg[j]) * KK[r][j] : 0
//   rhs_j    = beta_j * (v_j - exp(lg[j]) * KS0_j)
//   (I + M) U = rhs  (fp32 forward substitution, lane = value column e)
//   O_j = exp(lg[j-1]) * QS0_j + sum_{s<j} exp(lg[j-1]-lg[s]) QK[j][s] U_s
//         + auxw_j * v_j
//   S  = exp(lg[63]) * S + sum_s exp(lg[63]-lg[s]) k_s U_s^T
// State kept fp32 in LDS as S^T[e][d]; bf16 copies for MFMA operands.
// ---------------------------------------------------------------------------
__global__ __launch_bounds__(64) void k_scan2(
    const float* __restrict__ qr, const float* __restrict__ kr,
    const float* __restrict__ vr, const float4* __restrict__ aux,
    float* __restrict__ obuf) {
  const int bh = blockIdx.x;
  const int lane = threadIdx.x;
  const float* qB = qr + (size_t)bh * T_LEN * DHD;
  const float* kB = kr + (size_t)bh * T_LEN * DHD;
  const float* vB = vr + (size_t)bh * T_LEN * DHD;
  const float4* auxB = aux + (size_t)bh * T_LEN;
  float* oB = obuf + (size_t)bh * T_LEN * DHD;

  __shared__ __bf16 k_b[64 * 72];   // K [t][d]
  __shared__ __bf16 q_b[64 * 72];   // Q [t][d]; reused as C_b (masked scaled QK) after phase 2
  __shared__ __bf16 U_b[64 * 72];   // U^T [e][s]
  __shared__ __bf16 kT_b[64 * 72];  // scaled K^T [d][s]
  __shared__ __bf16 ST_b[64 * 72];  // S^T [e][d] bf16
  __shared__ float  vS[64 * 64];    // V [t][e]
  __shared__ float  KS0S[64 * 64];  // K@S0 [t][e]
  __shared__ float  STf[64 * 68];   // S^T [e][d] fp32 (persistent)
  __shared__ float  KKf[64 * 68];   // K K^T [t][s]
  __shared__ float  MTf[64 * 68];   // MT [j][r] (= M^T, zero for r<=j)
  __shared__ float  QKf[64 * 68];   // Q K^T [t][s]
  __shared__ float  lgS[64], pvS[64], beS[64], awS[64], enS[64];

  __bf16* C_b = q_b;

  // zero state
#pragma unroll
  for (int r = 0; r < 64; r++) STf[r * 68 + lane] = 0.f;
  __syncthreads();

  for (int c = 0; c < 16; c++) {
    const int t0 = c * 64;
    // ---- phase 1: aux + prefix decay, global loads, ST_b build ----
    float4 a4 = auxB[t0 + lane];
    float lg = logf(a4.x);
#pragma unroll
    for (int off = 1; off < 64; off <<= 1) {
      float tv = __shfl_up(lg, off);
      if (lane >= off) lg += tv;
    }
    float pv = __shfl_up(lg, 1);
    if (lane == 0) pv = 0.f;
    float lgTot = __shfl(lg, 63);
    lgS[lane] = lg; pvS[lane] = pv; beS[lane] = a4.y; awS[lane] = a4.w;
    enS[lane] = expf(lgTot - lg);

#pragma unroll
    for (int p = 0; p < 8; p++) {
      int s = p * 64 + lane;
      int row = s >> 3, col8 = s & 7;
      const float* gq = qB + (size_t)(t0 + row) * 64 + col8 * 8;
      const float* gk = kB + (size_t)(t0 + row) * 64 + col8 * 8;
      const float* gv = vB + (size_t)(t0 + row) * 64 + col8 * 8;
      float4 q0 = *(const float4*)gq, q1 = *(const float4*)(gq + 4);
      float4 k0 = *(const float4*)gk, k1 = *(const float4*)(gk + 4);
      float4 v0 = *(const float4*)gv, v1 = *(const float4*)(gv + 4);
      union { __bf16 h[8]; uint4 u; } pq, pk;
      pq.h[0] = (__bf16)q0.x; pq.h[1] = (__bf16)q0.y; pq.h[2] = (__bf16)q0.z; pq.h[3] = (__bf16)q0.w;
      pq.h[4] = (__bf16)q1.x; pq.h[5] = (__bf16)q1.y; pq.h[6] = (__bf16)q1.z; pq.h[7] = (__bf16)q1.w;
      pk.h[0] = (__bf16)k0.x; pk.h[1] = (__bf16)k0.y; pk.h[2] = (__bf16)k0.z; pk.h[3] = (__bf16)k0.w;
      pk.h[4] = (__bf16)k1.x; pk.h[5] = (__bf16)k1.y; pk.h[6] = (__bf16)k1.z; pk.h[7] = (__bf16)k1.w;
      *(uint4*)&q_b[row * 72 + col8 * 8] = pq.u;
      *(uint4*)&k_b[row * 72 + col8 * 8] = pk.u;
      *(float4*)&vS[row * 64 + col8 * 8] = v0;
      *(float4*)&vS[row * 64 + col8 * 8 + 4] = v1;
    }
    // ST_b from STf (lane = e)
#pragma unroll
    for (int d8 = 0; d8 < 8; d8++) {
      float4 s0 = *(const float4*)&STf[lane * 68 + d8 * 8];
      float4 s1 = *(const float4*)&STf[lane * 68 + d8 * 8 + 4];
      union { __bf16 h[8]; uint4 u; } ps;
      ps.h[0] = (__bf16)s0.x; ps.h[1] = (__bf16)s0.y; ps.h[2] = (__bf16)s0.z; ps.h[3] = (__bf16)s0.w;
      ps.h[4] = (__bf16)s1.x; ps.h[5] = (__bf16)s1.y; ps.h[6] = (__bf16)s1.z; ps.h[7] = (__bf16)s1.w;
      *(uint4*)&ST_b[lane * 72 + d8 * 8] = ps.u;
    }
    __syncthreads();

    // ---- phase 2: MFMAs: KK, QK, KS0 (to LDS), QS0 (regs) ----
    f32x4 qs0[4][4];
#pragma unroll
    for (int mi = 0; mi < 4; mi++)
#pragma unroll
      for (int ni = 0; ni < 4; ni++) {
        f32x4 akk = {0.f, 0.f, 0.f, 0.f};
        f32x4 aqk = {0.f, 0.f, 0.f, 0.f};
        f32x4 aks = {0.f, 0.f, 0.f, 0.f};
        f32x4 aqs = {0.f, 0.f, 0.f, 0.f};
#pragma unroll
        for (int ks = 0; ks < 2; ks++) {
          bf16x8 fa_k = *(const bf16x8*)&k_b[(mi * 16 + (lane & 15)) * 72 + ks * 32 + (lane >> 4) * 8];
          bf16x8 fa_q = *(const bf16x8*)&q_b[(mi * 16 + (lane & 15)) * 72 + ks * 32 + (lane >> 4) * 8];
          bf16x8 fb_k = *(const bf16x8*)&k_b[(ni * 16 + (lane & 15)) * 72 + ks * 32 + (lane >> 4) * 8];
          bf16x8 fb_s = *(const bf16x8*)&ST_b[(ni * 16 + (lane & 15)) * 72 + ks * 32 + (lane >> 4) * 8];
          akk = __builtin_amdgcn_mfma_f32_16x16x32_bf16(fa_k, fb_k, akk, 0, 0, 0);
          aqk = __builtin_amdgcn_mfma_f32_16x16x32_bf16(fa_q, fb_k, aqk, 0, 0, 0);
          aks = __builtin_amdgcn_mfma_f32_16x16x32_bf16(fa_k, fb_s, aks, 0, 0, 0);
          aqs = __builtin_amdgcn_mfma_f32_16x16x32_bf16(fa_q, fb_s, aqs, 0, 0, 0);
        }
        qs0[mi][ni] = aqs;
#pragma unroll
        for (int r = 0; r < 4; r++) {
          int row = mi * 16 + (lane >> 4) * 4 + r;
          int col = ni * 16 + (lane & 15);
          KKf[row * 68 + col] = akk[r];
          QKf[row * 68 + col] = aqk[r];
          KS0S[row * 64 + col] = aks[r];
        }
      }
    __syncthreads();

    // ---- phase 3: rhs (regs), MT fold, C fold ----
    float u[64];
#pragma unroll
    for (int j = 0; j < 64; j++)
      u[j] = beS[j] * (vS[j * 64 + lane] - expf(lgS[j]) * KS0S[j * 64 + lane]);

    {  // MT fold: lane owns column j=lane of M -> row of MT
      float lgj = lgS[lane];
#pragma unroll
      for (int r4 = 0; r4 < 16; r4++) {
        float4 m4;
#pragma unroll
        for (int q = 0; q < 4; q++) {
          int r = r4 * 4 + q;
          float m = 0.f;
          if (r > lane) m = beS[r] * expf(lgS[r] - lgj) * KKf[r * 68 + lane];
          ((float*)&m4)[q] = m;
        }
        *(float4*)&MTf[lane * 68 + r4 * 4] = m4;
      }
    }
    {  // C fold: lane owns row t=lane; C[t][s] = (s<t) exp(pv_t - lg_s) QK[t][s]
      float pvt = pvS[lane];
#pragma unroll
      for (int s8 = 0; s8 < 8; s8++) {
        union { __bf16 h[8]; uint4 u; } pc;
#pragma unroll
        for (int q = 0; q < 8; q++) {
          int s = s8 * 8 + q;
          float cv = (s < lane) ? expf(pvt - lgS[s]) * QKf[lane * 68 + s] : 0.f;
          pc.h[q] = (__bf16)cv;
        }
        *(uint4*)&C_b[lane * 72 + s8 * 8] = pc.u;
      }
    }
    __syncthreads();

    // ---- phase 4: forward substitution (lane = e), write U_b rows ----
#pragma unroll
    for (int j = 0; j < 64; j++) {
      U_b[lane * 72 + j] = (__bf16)u[j];
      float uj = u[j];
#pragma unroll
      for (int g = (j >> 4); g < 4; g++) {
#pragma unroll
        for (int q4 = 0; q4 < 4; q4++) {
          const float4 m4 = *(const float4*)&MTf[j * 68 + g * 16 + q4 * 4];
          u[g * 16 + q4 * 4 + 0] -= m4.x * uj;
          u[g * 16 + q4 * 4 + 1] -= m4.y * uj;
          u[g * 16 + q4 * 4 + 2] -= m4.z * uj;
          u[g * 16 + q4 * 4 + 3] -= m4.w * uj;
        }
      }
    }
    __syncthreads();

    // ---- phase 5: O = scaled QS0 + C@U + auxw*v, store ----
#pragma unroll
    for (int mi = 0; mi < 4; mi++)
#pragma unroll
      for (int r = 0; r < 4; r++) {
        int j = mi * 16 + (lane >> 4) * 4 + r;
        float sc = expf(pvS[j]);
#pragma unroll
        for (int ni = 0; ni < 4; ni++) qs0[mi][ni][r] *= sc;
      }
#pragma unroll
    for (int mi = 0; mi < 4; mi++)
#pragma unroll
      for (int ni = 0; ni < 4; ni++) {
#pragma unroll
        for (int ks = 0; ks < 2; ks++) {
          bf16x8 fa = *(const bf16x8*)&C_b[(mi * 16 + (lane & 15)) * 72 + ks * 32 + (lane >> 4) * 8];
          bf16x8 fb = *(const bf16x8*)&U_b[(ni * 16 + (lane & 15)) * 72 + ks * 32 + (lane >> 4) * 8];
          qs0[mi][ni] = __builtin_amdgcn_mfma_f32_16x16x32_bf16(fa, fb, qs0[mi][ni], 0, 0, 0);
        }
#pragma unroll
        for (int r = 0; r < 4; r++) {
          int j = mi * 16 + (lane >> 4) * 4 + r;
          int col = ni * 16 + (lane & 15);
          float ov = qs0[mi][ni][r] + awS[j] * vS[j * 64 + col];
          oB[(size_t)(t0 + j) * 64 + col] = ov;
        }
      }

    // ---- phase 6: scaled K^T build (lane = d) ----
#pragma unroll
    for (int t8 = 0; t8 < 8; t8++) {
      union { __bf16 h[8]; uint4 u; } pt;
#pragma unroll
      for (int q = 0; q < 8; q++) {
        int t = t8 * 8 + q;
        float kv = (float)k_b[t * 72 + lane] * enS[t];
        pt.h[q] = (__bf16)kv;
      }
      *(uint4*)&kT_b[lane * 72 + t8 * 8] = pt.u;
    }
    __syncthreads();

    // ---- phase 7: state update S^T = exp(lgTot)*S^T + U_b @ kT_b ----
    {
      float gC = expf(lgTot);
#pragma unroll
      for (int mi = 0; mi < 4; mi++)
#pragma unroll
        for (int ni = 0; ni < 4; ni++) {
          f32x4 sacc = {0.f, 0.f, 0.f, 0.f};
#pragma unroll
          for (int ks = 0; ks < 2; ks++) {
            bf16x8 fa = *(const bf16x8*)&U_b[(mi * 16 + (lane & 15)) * 72 + ks * 32 + (lane >> 4) * 8];
            bf16x8 fb = *(const bf16x8*)&kT_b[(ni * 16 + (lane & 15)) * 72 + ks * 32 + (lane >> 4) * 8];
            sacc = __builtin_amdgcn_mfma_f32_16x16x32_bf16(fa, fb, sacc, 0, 0, 0);
          }
#pragma unroll
          for (int r = 0; r < 4; r++) {
            int e = mi * 16 + (lane >> 4) * 4 + r;
            int d = ni * 16 + (lane & 15);
            STf[e * 68 + d] = gC * STf[e * 68 + d] + sacc[r];
          }
        }
    }
    __syncthreads();
  }
}

// ---------------------------------------------------------------------------
// K9: output RMS-norm + gate, writes bf16 hi/lo pair
// ---------------------------------------------------------------------------
__global__ __launch_bounds__(256) void k_outnorm(
    const float* __restrict__ obuf, const float* __restrict__ g,
    const float* __restrict__ onw, __bf16* __restrict__ rh,
    __bf16* __restrict__ rl) {
  int widx = blockIdx.x * 4 + (threadIdx.x >> 6);
  int lane = threadIdx.x & 63;
  int h = widx & 15, bt = widx >> 4;
  int t = bt & 1023, b = bt >> 10;
  float ov = obuf[(((size_t)(b * 16 + h)) * 1024 + t) * 64 + lane];
  float ss = ov * ov;
#pragma unroll
  for (int m = 1; m < 64; m <<= 1) ss += __shfl_xor(ss, m);
  float on = ov * rsqrtf(ss * (1.f / 64.f) + 1e-6f) * onw[lane];
  float sil = on / (1.f + expf(-on));
  float gv = g[(size_t)bt * 1024 + h * 64 + lane];
  float r = gv * sil;
  __bf16 hv = (__bf16)r;
  rh[(size_t)bt * 1024 + h * 64 + lane] = hv;
  rl[(size_t)bt * 1024 + h * 64 + lane] = (__bf16)(r - (float)hv);
}

// ---------------------------------------------------------------------------
extern "C" void kernel_launch(void* const* d_in, const int* in_sizes, int n_in,
                              void* d_out, int out_size, void* d_ws, size_t ws_size,
                              hipStream_t stream) {
  (void)in_sizes; (void)n_in; (void)out_size; (void)ws_size;
  const float* x    = (const float*)d_in[0];
  const float* Wq   = (const float*)d_in[1];
  const float* Wk   = (const float*)d_in[2];
  const float* Wv   = (const float*)d_in[3];
  const float* Wg   = (const float*)d_in[4];
  const float* Wo   = (const float*)d_in[5];
  const float* bw   = (const float*)d_in[6];
  const float* bb   = (const float*)d_in[7];
  const float* gkw  = (const float*)d_in[8];
  const float* gkb  = (const float*)d_in[9];
  const float* qcw  = (const float*)d_in[10];
  const float* qcb  = (const float*)d_in[11];
  const float* kcw  = (const float*)d_in[12];
  const float* kcb  = (const float*)d_in[13];
  const float* vcw  = (const float*)d_in[14];
  const float* vcb  = (const float*)d_in[15];
  const float* A_log= (const float*)d_in[16];
  const float* Dp   = (const float*)d_in[17];
  const float* dtb  = (const float*)d_in[18];
  const float* onw  = (const float*)d_in[19];

  char* ws = (char*)d_ws;
  const size_t MB = 1024 * 1024;
  __bf16* xb_h = (__bf16*)(ws + 0);
  __bf16* xb_l = (__bf16*)(ws + 4 * MB);
  __bf16* Wq_h = (__bf16*)(ws + 8 * MB);
  __bf16* Wq_l = (__bf16*)(ws + 10 * MB);
  __bf16* Wk_h = (__bf16*)(ws + 12 * MB);
  __bf16* Wk_l = (__bf16*)(ws + 14 * MB);
  __bf16* Wv_h = (__bf16*)(ws + 16 * MB);
  __bf16* Wv_l = (__bf16*)(ws + 18 * MB);
  __bf16* Wg_h = (__bf16*)(ws + 20 * MB);
  __bf16* Wg_l = (__bf16*)(ws + 22 * MB);
  __bf16* Wo_h = (__bf16*)(ws + 24 * MB);
  __bf16* Wo_l = (__bf16*)(ws + 26 * MB);
  float* q_pre = (float*)(ws + 28 * MB);
  float* k_pre = (float*)(ws + 36 * MB);
  float* v_pre = (float*)(ws + 44 * MB);
  float* g_buf = (float*)(ws + 52 * MB);
  float* qc    = (float*)(ws + 0);
  float* kc    = (float*)(ws + 8 * MB);
  float* vr    = (float*)(ws + 16 * MB);
  float* qrb   = q_pre;
  float* krb   = k_pre;
  float* obuf  = v_pre;
  __bf16* r_h  = (__bf16*)(ws + 0);
  __bf16* r_l  = (__bf16*)(ws + 4 * MB);
  float* alphaB = (float*)(ws + 60 * MB);
  float* betaB  = (float*)(ws + 60 * MB + 128 * 1024);
  float4* aux   = (float4*)(ws + 60 * MB + 256 * 1024);
  float* ct     = (float*)(ws + 60 * MB + 768 * 1024);
  float* st     = (float*)(ws + 60 * MB + 896 * 1024);
  float* out    = (float*)d_out;

  k_tobf16_split<<<1024, 256, 0, stream>>>(x, xb_h, xb_l, 262144);
  k_transp_split<<<dim3(16, 16, 5), 256, 0, stream>>>(
      Wq, Wk, Wv, Wg, Wo,
      Wq_h, Wk_h, Wv_h, Wg_h, Wo_h,
      Wq_l, Wk_l, Wv_l, Wg_l, Wo_l);
  k_rope_table<<<128, 256, 0, stream>>>(ct, st);
  k_gates<<<2048, 256, 0, stream>>>(x, bw, bb, gkw, gkb, A_log, dtb, alphaB, betaB);
  k_gemm3<<<dim3(8, 16, 4), 256, 0, stream>>>(
      xb_h, xb_l,
      Wq_h, Wk_h, Wv_h, Wg_h,
      Wq_l, Wk_l, Wv_l, Wg_l,
      q_pre, k_pre, v_pre, g_buf, 1024, 1024);
  k_conv<<<dim3(8192, 3), 256, 0, stream>>>(q_pre, k_pre, v_pre, qcw, kcw, vcw,
                                            qcb, kcb, vcb, qc, kc, vr);
  k_ropenorm<<<8192, 256, 0, stream>>>(qc, kc, ct, st, alphaB, betaB, Dp, qrb, krb, aux);
  k_scan2<<<32, 64, 0, stream>>>(qrb, krb, vr, aux, obuf);
  k_outnorm<<<8192, 256, 0, stream>>>(obuf, g_buf, onw, r_h, r_l);
  k_gemm3<<<dim3(8, 16, 1), 256, 0, stream>>>(
      r_h, r_l,
      Wo_h, Wo_h, Wo_h, Wo_h,
      Wo_l, Wo_l, Wo_l, Wo_l,
      out, out, out, out, 1024, 1024);
}

// Round 5
// 343.697 us; speedup vs baseline: 4.9773x; 2.2825x over previous
//
#include <hip/hip_runtime.h>
#include <hip/hip_bf16.h>
#include <cstdint>

// Problem constants
#define T_LEN 1024
#define HIDN  1024
#define NH    16
#define DHD   64

typedef __bf16 bf16x8 __attribute__((ext_vector_type(8)));
typedef float  f32x4  __attribute__((ext_vector_type(4)));

// ---------------------------------------------------------------------------
// K1: fp32 -> bf16 hi/lo split (x), vectorized 8/thread
// ---------------------------------------------------------------------------
__global__ __launch_bounds__(256) void k_tobf16_split(const float* __restrict__ in,
                                                      __bf16* __restrict__ hi,
                                                      __bf16* __restrict__ lo, int n8) {
  int i = blockIdx.x * 256 + threadIdx.x;
  if (i >= n8) return;
  const float4* p = (const float4*)in + (size_t)i * 2;
  float4 a = p[0], b = p[1];
  float v[8] = {a.x, a.y, a.z, a.w, b.x, b.y, b.z, b.w};
  union { __bf16 h[8]; uint4 u; } ph, pl;
#pragma unroll
  for (int j = 0; j < 8; j++) {
    __bf16 h = (__bf16)v[j];
    ph.h[j] = h;
    pl.h[j] = (__bf16)(v[j] - (float)h);
  }
  ((uint4*)hi)[i] = ph.u;
  ((uint4*)lo)[i] = pl.u;
}

// ---------------------------------------------------------------------------
// K2: transpose 1024x1024 f32 W[k][n] -> bf16 hi/lo Wt[n][k] (5 weights via z)
// ---------------------------------------------------------------------------
__global__ __launch_bounds__(256) void k_transp_split(
    const float* __restrict__ W0, const float* __restrict__ W1,
    const float* __restrict__ W2, const float* __restrict__ W3,
    const float* __restrict__ W4,
    __bf16* __restrict__ H0, __bf16* __restrict__ H1, __bf16* __restrict__ H2,
    __bf16* __restrict__ H3, __bf16* __restrict__ H4,
    __bf16* __restrict__ L0, __bf16* __restrict__ L1, __bf16* __restrict__ L2,
    __bf16* __restrict__ L3, __bf16* __restrict__ L4) {
  const float* W; __bf16* Th; __bf16* Tl;
  switch (blockIdx.z) {
    case 0: W = W0; Th = H0; Tl = L0; break;
    case 1: W = W1; Th = H1; Tl = L1; break;
    case 2: W = W2; Th = H2; Tl = L2; break;
    case 3: W = W3; Th = H3; Tl = L3; break;
    default: W = W4; Th = H4; Tl = L4; break;
  }
  __shared__ float tile[64][65];
  int tid = threadIdx.x;
  int r0 = tid >> 4;          // 0..15
  int c0 = (tid & 15) * 4;    // 0..60
  int kbase = blockIdx.y * 64, nbase = blockIdx.x * 64;
#pragma unroll
  for (int rr = 0; rr < 4; rr++) {
    int r = r0 + rr * 16;
    float4 v = *(const float4*)(W + (size_t)(kbase + r) * 1024 + nbase + c0);
    tile[r][c0 + 0] = v.x; tile[r][c0 + 1] = v.y;
    tile[r][c0 + 2] = v.z; tile[r][c0 + 3] = v.w;
  }
  __syncthreads();
#pragma unroll
  for (int rr = 0; rr < 4; rr++) {
    int n = r0 + rr * 16;
    union { __bf16 h[4]; unsigned long long u; } ph, pl;
#pragma unroll
    for (int j = 0; j < 4; j++) {
      float v = tile[c0 + j][n];
      __bf16 h = (__bf16)v;
      ph.h[j] = h;
      pl.h[j] = (__bf16)(v - (float)h);
    }
    *(unsigned long long*)(Th + (size_t)(nbase + n) * 1024 + kbase + c0) = ph.u;
    *(unsigned long long*)(Tl + (size_t)(nbase + n) * 1024 + kbase + c0) = pl.u;
  }
}

// ---------------------------------------------------------------------------
// K3: split-precision bf16 MFMA GEMM (3 cross terms, lo*lo dropped)
// ---------------------------------------------------------------------------
#define LDT 40
__global__ __launch_bounds__(256) void k_gemm3(
    const __bf16* __restrict__ Ah, const __bf16* __restrict__ Al,
    const __bf16* __restrict__ Bh0, const __bf16* __restrict__ Bh1,
    const __bf16* __restrict__ Bh2, const __bf16* __restrict__ Bh3,
    const __bf16* __restrict__ Bl0, const __bf16* __restrict__ Bl1,
    const __bf16* __restrict__ Bl2, const __bf16* __restrict__ Bl3,
    float* __restrict__ C0, float* __restrict__ C1,
    float* __restrict__ C2, float* __restrict__ C3,
    int Kdim, int Ncols) {
  const __bf16* Bh; const __bf16* Bl; float* C;
  switch (blockIdx.z) {
    case 0: Bh = Bh0; Bl = Bl0; C = C0; break;
    case 1: Bh = Bh1; Bl = Bl1; C = C1; break;
    case 2: Bh = Bh2; Bl = Bl2; C = C2; break;
    default: Bh = Bh3; Bl = Bl3; C = C3; break;
  }
  __shared__ __bf16 Ash[128 * LDT];
  __shared__ __bf16 Asl[128 * LDT];
  __shared__ __bf16 Bsh[128 * LDT];
  __shared__ __bf16 Bsl[128 * LDT];
  const int tid = threadIdx.x;
  const int lane = tid & 63;
  const int wave = tid >> 6;
  const int wr = wave >> 1, wc = wave & 1;
  const int rowA0 = blockIdx.y * 128;
  const int colB0 = blockIdx.x * 128;
  const int sseg = tid & 3;
  const int srow0 = tid >> 2;
  const int srow1 = srow0 + 64;

  f32x4 acc[4][4] = {};

  for (int k0 = 0; k0 < Kdim; k0 += 32) {
    size_t a0 = (size_t)(rowA0 + srow0) * Kdim + k0 + sseg * 8;
    size_t a1 = (size_t)(rowA0 + srow1) * Kdim + k0 + sseg * 8;
    size_t b0 = (size_t)(colB0 + srow0) * Kdim + k0 + sseg * 8;
    size_t b1 = (size_t)(colB0 + srow1) * Kdim + k0 + sseg * 8;
    uint4 rah0 = *(const uint4*)(Ah + a0);
    uint4 rah1 = *(const uint4*)(Ah + a1);
    uint4 ral0 = *(const uint4*)(Al + a0);
    uint4 ral1 = *(const uint4*)(Al + a1);
    uint4 rbh0 = *(const uint4*)(Bh + b0);
    uint4 rbh1 = *(const uint4*)(Bh + b1);
    uint4 rbl0 = *(const uint4*)(Bl + b0);
    uint4 rbl1 = *(const uint4*)(Bl + b1);
    __syncthreads();
    *(uint4*)&Ash[srow0 * LDT + sseg * 8] = rah0;
    *(uint4*)&Ash[srow1 * LDT + sseg * 8] = rah1;
    *(uint4*)&Asl[srow0 * LDT + sseg * 8] = ral0;
    *(uint4*)&Asl[srow1 * LDT + sseg * 8] = ral1;
    *(uint4*)&Bsh[srow0 * LDT + sseg * 8] = rbh0;
    *(uint4*)&Bsh[srow1 * LDT + sseg * 8] = rbh1;
    *(uint4*)&Bsl[srow0 * LDT + sseg * 8] = rbl0;
    *(uint4*)&Bsl[srow1 * LDT + sseg * 8] = rbl1;
    __syncthreads();
    bf16x8 afh[4], afl[4], bfh[4], bfl[4];
#pragma unroll
    for (int mi = 0; mi < 4; mi++) {
      int off = (wr * 64 + mi * 16 + (lane & 15)) * LDT + (lane >> 4) * 8;
      afh[mi] = *(const bf16x8*)&Ash[off];
      afl[mi] = *(const bf16x8*)&Asl[off];
    }
#pragma unroll
    for (int ni = 0; ni < 4; ni++) {
      int off = (wc * 64 + ni * 16 + (lane & 15)) * LDT + (lane >> 4) * 8;
      bfh[ni] = *(const bf16x8*)&Bsh[off];
      bfl[ni] = *(const bf16x8*)&Bsl[off];
    }
#pragma unroll
    for (int mi = 0; mi < 4; mi++)
#pragma unroll
      for (int ni = 0; ni < 4; ni++) {
        acc[mi][ni] = __builtin_amdgcn_mfma_f32_16x16x32_bf16(afh[mi], bfh[ni], acc[mi][ni], 0, 0, 0);
        acc[mi][ni] = __builtin_amdgcn_mfma_f32_16x16x32_bf16(afl[mi], bfh[ni], acc[mi][ni], 0, 0, 0);
        acc[mi][ni] = __builtin_amdgcn_mfma_f32_16x16x32_bf16(afh[mi], bfl[ni], acc[mi][ni], 0, 0, 0);
      }
  }
#pragma unroll
  for (int mi = 0; mi < 4; mi++)
#pragma unroll
    for (int ni = 0; ni < 4; ni++) {
      int col = colB0 + wc * 64 + ni * 16 + (lane & 15);
#pragma unroll
      for (int r = 0; r < 4; r++) {
        int row = rowA0 + wr * 64 + mi * 16 + (lane >> 4) * 4 + r;
        C[(size_t)row * Ncols + col] = acc[mi][ni][r];
      }
    }
}

// ---------------------------------------------------------------------------
// K4: gates
// ---------------------------------------------------------------------------
__global__ __launch_bounds__(256) void k_gates(
    const float* __restrict__ x, const float* __restrict__ bw,
    const float* __restrict__ bb, const float* __restrict__ gkw,
    const float* __restrict__ gkb, const float* __restrict__ A_log,
    const float* __restrict__ dt_bias,
    float* __restrict__ alphaB, float* __restrict__ betaB) {
  const int bt = blockIdx.x;
  const int tid = threadIdx.x;
  const int h = tid & 15;
  const int chunk = tid >> 4;
  const float* xr = x + (size_t)bt * HIDN;
  float d1 = 0.f, d2 = 0.f;
#pragma unroll 8
  for (int j = 0; j < 64; j++) {
    int k = chunk * 64 + j;
    float xv = xr[k];
    d1 += xv * bw[k * 16 + h];
    d2 += xv * gkw[k * 16 + h];
  }
  __shared__ float p1[16][16], p2[16][16];
  p1[chunk][h] = d1; p2[chunk][h] = d2;
  __syncthreads();
  if (tid < 16) {
    float s1 = 0.f, s2 = 0.f;
#pragma unroll
    for (int c = 0; c < 16; c++) { s1 += p1[c][tid]; s2 += p2[c][tid]; }
    float beta = 1.f / (1.f + expf(-(s1 + bb[tid])));
    float z = s2 + gkb[tid] + dt_bias[tid];
    float sp = fmaxf(z, 0.f) + log1pf(expf(-fabsf(z)));
    float alpha = expf(-expf(A_log[tid]) * sp);
    alphaB[(size_t)bt * 16 + tid] = alpha;
    betaB[(size_t)bt * 16 + tid] = beta;
  }
}

// ---------------------------------------------------------------------------
// K5: rope tables
// ---------------------------------------------------------------------------
__global__ __launch_bounds__(256) void k_rope_table(float* __restrict__ ct,
                                                    float* __restrict__ st) {
  int idx = blockIdx.x * 256 + threadIdx.x;
  if (idx >= T_LEN * 32) return;
  int t = idx >> 5, i = idx & 31;
  int m = 2 * (i & 15);
  float f = expf(-(float)m * (9.210340371976184f / 32.f));
  float ang = (float)t * f;
  ct[idx] = cosf(ang);
  st[idx] = sinf(ang);
}

// ---------------------------------------------------------------------------
// K6: causal depthwise conv (K=4) + bias + SiLU
// ---------------------------------------------------------------------------
__global__ __launch_bounds__(256) void k_conv(
    const float* __restrict__ in0, const float* __restrict__ in1,
    const float* __restrict__ in2,
    const float* __restrict__ w0, const float* __restrict__ w1,
    const float* __restrict__ w2,
    const float* __restrict__ b0, const float* __restrict__ b1,
    const float* __restrict__ b2,
    float* __restrict__ o0, float* __restrict__ o1, float* __restrict__ o2) {
  const int tensor = blockIdx.y;
  const float* in; const float* w; const float* bias; float* out;
  switch (tensor) {
    case 0: in = in0; w = w0; bias = b0; out = o0; break;
    case 1: in = in1; w = w1; bias = b1; out = o1; break;
    default: in = in2; w = w2; bias = b2; out = o2; break;
  }
  int idx = blockIdx.x * 256 + threadIdx.x;
  int c = idx & 1023;
  int bt = idx >> 10;
  int t = bt & 1023, b = bt >> 10;
  float4 wc4 = *(const float4*)(w + (size_t)c * 4);
  const float* col = in + ((size_t)b * 1024) * 1024 + c;
  float xm3 = (t >= 3) ? col[(size_t)(t - 3) * 1024] : 0.f;
  float xm2 = (t >= 2) ? col[(size_t)(t - 2) * 1024] : 0.f;
  float xm1 = (t >= 1) ? col[(size_t)(t - 1) * 1024] : 0.f;
  float x0 = col[(size_t)t * 1024];
  float acc = bias[c] + wc4.x * xm3 + wc4.y * xm2 + wc4.z * xm1 + wc4.w * x0;
  float y = acc / (1.f + expf(-acc));
  if (tensor < 2) {
    out[(size_t)bt * 1024 + c] = y;
  } else {
    int h = c >> 6, d = c & 63;
    out[(((size_t)(b * 16 + h)) * 1024 + t) * 64 + d] = y;
  }
}

// ---------------------------------------------------------------------------
// K7: RoPE + L2-norm for q,k; packs aux = {alpha, beta, alpha*beta, D*(q.k)}
// ---------------------------------------------------------------------------
__global__ __launch_bounds__(256) void k_ropenorm(
    const float* __restrict__ qc, const float* __restrict__ kc,
    const float* __restrict__ ct, const float* __restrict__ st,
    const float* __restrict__ alphaB, const float* __restrict__ betaB,
    const float* __restrict__ Dp,
    float* __restrict__ qr, float* __restrict__ kr, float4* __restrict__ aux) {
  int widx = blockIdx.x * 4 + (threadIdx.x >> 6);
  int lane = threadIdx.x & 63;
  int h = widx & 15;
  int bt = widx >> 4;
  int t = bt & 1023, b = bt >> 10;
  const float* qrow = qc + (size_t)bt * 1024 + h * 64;
  const float* krow = kc + (size_t)bt * 1024 + h * 64;
  int i = lane & 31;
  float cv = ct[t * 32 + i], sv = st[t * 32 + i];
  float q1 = qrow[2 * i], q2 = qrow[2 * i + 1];
  float k1 = krow[2 * i], k2 = krow[2 * i + 1];
  float qo = (lane < 32) ? (q1 * cv - q2 * sv) : (q1 * sv + q2 * cv);
  float ko = (lane < 32) ? (k1 * cv - k2 * sv) : (k1 * sv + k2 * cv);
  float qs = qo * qo, ks2 = ko * ko;
#pragma unroll
  for (int m = 1; m < 64; m <<= 1) { qs += __shfl_xor(qs, m); ks2 += __shfl_xor(ks2, m); }
  float qn = qo * rsqrtf(qs + 1e-6f);
  float kn = ko * rsqrtf(ks2 + 1e-6f);
  float dq = qn * kn;
#pragma unroll
  for (int m = 1; m < 64; m <<= 1) dq += __shfl_xor(dq, m);
  size_t obase = ((size_t)(b * 16 + h) * 1024 + t) * 64;
  qr[obase + lane] = qn;
  kr[obase + lane] = kn;
  if (lane == 0) {
    float alpha = alphaB[(size_t)bt * 16 + h];
    float beta = betaB[(size_t)bt * 16 + h];
    aux[(size_t)(b * 16 + h) * 1024 + t] = make_float4(alpha, beta, alpha * beta, Dp[h] * dq);
  }
}

// ---------------------------------------------------------------------------
// K8a: WY-form scan, S0-independent per-chunk work. Grid = 512 (bh*16+c),
// 2 waves. Produces (per chunk, 64x64 each):
//   BcT[e][d] = (K''^T U0)^T,  Ac[d][d'] = K''^T W,
//   O1[t][e]  = C@U0 + aw*v (written to obuf),  Qeff[t][d] = Q' - C@W
// where (I+M)U0 = beta*V, (I+M)W = diag(beta*gamma)K,
//   M[r][s] = beta_r e^{lg_r-lg_s} KK[r][s] (s<r),
//   C[t][s] = e^{pv_t-lg_s} QK[t][s] (s<t), Q'[t] = e^{pv_t} q_t,
//   K''[s]  = e^{lgTot-lg_s} k_s.
// ---------------------------------------------------------------------------
__global__ __launch_bounds__(128) void k_scanA(
    const float* __restrict__ qr, const float* __restrict__ kr,
    const float* __restrict__ vr, const float4* __restrict__ aux,
    float* __restrict__ O1, float* __restrict__ AcF,
    float* __restrict__ BcTF, float* __restrict__ QeffF,
    float* __restrict__ gcF) {
  const int bid = blockIdx.x;
  const int bh = bid >> 4, c = bid & 15;
  const int t0 = c * 64;
  const int tid = threadIdx.x;
  const int w = tid >> 6, lane = tid & 63;
  const float* qB = qr + (size_t)bh * 65536 + (size_t)t0 * 64;
  const float* kB = kr + (size_t)bh * 65536 + (size_t)t0 * 64;
  const float* vB = vr + (size_t)bh * 65536 + (size_t)t0 * 64;
  const float4* auxB = aux + (size_t)bh * T_LEN + t0;

  __shared__ __bf16 q_b[64 * 72];   // Q [t][d]
  __shared__ __bf16 k_b[64 * 72];   // K [t][d]
  __shared__ __bf16 kT_b[64 * 72];  // K''^T [d][s]
  __shared__ __bf16 C_b[64 * 72];   // C [t][s] (strictly-lower scaled QK)
  __shared__ __bf16 U0T[64 * 72];   // U0^T [e][s]
  __shared__ __bf16 WT[64 * 72];    // W^T [d][s]
  __shared__ float  vS[64 * 64];    // V [t][e]
  __shared__ float  MTf[64 * 68];   // MT [j][r] = M[r][j] (0 for r<=j)
  __shared__ float  lgS[64], pvS[64], beS[64], awS[64], enS[64];

  // ---- phase 1: aux + prefix decay (wave 0), global loads (both) ----
  if (w == 0) {
    float4 a4 = auxB[lane];
    float lg = logf(a4.x);
#pragma unroll
    for (int off = 1; off < 64; off <<= 1) {
      float tv = __shfl_up(lg, off);
      if (lane >= off) lg += tv;
    }
    float pv = __shfl_up(lg, 1);
    if (lane == 0) pv = 0.f;
    float lgTot = __shfl(lg, 63);
    lgS[lane] = lg; pvS[lane] = pv; beS[lane] = a4.y; awS[lane] = a4.w;
    enS[lane] = expf(lgTot - lg);
    if (lane == 0) gcF[bid] = expf(lgTot);
  }
#pragma unroll
  for (int p = 0; p < 4; p++) {
    int s = p * 128 + tid;
    int row = s >> 3, col8 = s & 7;
    const float* gq = qB + (size_t)row * 64 + col8 * 8;
    const float* gk = kB + (size_t)row * 64 + col8 * 8;
    const float* gv = vB + (size_t)row * 64 + col8 * 8;
    float4 q0 = *(const float4*)gq, q1 = *(const float4*)(gq + 4);
    float4 k0 = *(const float4*)gk, k1 = *(const float4*)(gk + 4);
    float4 v0 = *(const float4*)gv, v1 = *(const float4*)(gv + 4);
    union { __bf16 h[8]; uint4 u; } pq, pk;
    pq.h[0] = (__bf16)q0.x; pq.h[1] = (__bf16)q0.y; pq.h[2] = (__bf16)q0.z; pq.h[3] = (__bf16)q0.w;
    pq.h[4] = (__bf16)q1.x; pq.h[5] = (__bf16)q1.y; pq.h[6] = (__bf16)q1.z; pq.h[7] = (__bf16)q1.w;
    pk.h[0] = (__bf16)k0.x; pk.h[1] = (__bf16)k0.y; pk.h[2] = (__bf16)k0.z; pk.h[3] = (__bf16)k0.w;
    pk.h[4] = (__bf16)k1.x; pk.h[5] = (__bf16)k1.y; pk.h[6] = (__bf16)k1.z; pk.h[7] = (__bf16)k1.w;
    *(uint4*)&q_b[row * 72 + col8 * 8] = pq.u;
    *(uint4*)&k_b[row * 72 + col8 * 8] = pk.u;
    *(float4*)&vS[row * 64 + col8 * 8] = v0;
    *(float4*)&vS[row * 64 + col8 * 8 + 4] = v1;
  }
  __syncthreads();

  // ---- phase 2: KK->MT and QK->C, folds fused in MFMA epilogue ----
#pragma unroll
  for (int mm = 0; mm < 2; mm++) {
    int mi = w * 2 + mm;
#pragma unroll
    for (int ni = 0; ni < 4; ni++) {
      f32x4 akk = {0.f, 0.f, 0.f, 0.f};
      f32x4 aqk = {0.f, 0.f, 0.f, 0.f};
#pragma unroll
      for (int ks = 0; ks < 2; ks++) {
        bf16x8 fa_k = *(const bf16x8*)&k_b[(mi * 16 + (lane & 15)) * 72 + ks * 32 + (lane >> 4) * 8];
        bf16x8 fa_q = *(const bf16x8*)&q_b[(mi * 16 + (lane & 15)) * 72 + ks * 32 + (lane >> 4) * 8];
        bf16x8 fb_k = *(const bf16x8*)&k_b[(ni * 16 + (lane & 15)) * 72 + ks * 32 + (lane >> 4) * 8];
        akk = __builtin_amdgcn_mfma_f32_16x16x32_bf16(fa_k, fb_k, akk, 0, 0, 0);
        aqk = __builtin_amdgcn_mfma_f32_16x16x32_bf16(fa_q, fb_k, aqk, 0, 0, 0);
      }
#pragma unroll
      for (int r = 0; r < 4; r++) {
        int row = mi * 16 + (lane >> 4) * 4 + r;
        int col = ni * 16 + (lane & 15);
        float mt = 0.f, cv = 0.f;
        if (row > col) {
          mt = beS[row] * expf(lgS[row] - lgS[col]) * akk[r];
          cv = expf(pvS[row] - lgS[col]) * aqk[r];
        }
        MTf[col * 68 + row] = mt;
        C_b[row * 72 + col] = (__bf16)cv;
      }
    }
  }
  __syncthreads();

  // ---- phase 3: K''^T build (wave 1 only; consumed after next barrier) ----
  if (w == 1) {
#pragma unroll
    for (int t8 = 0; t8 < 8; t8++) {
      union { __bf16 h[8]; uint4 u; } pt;
#pragma unroll
      for (int q = 0; q < 8; q++) {
        int t = t8 * 8 + q;
        pt.h[q] = (__bf16)((float)k_b[t * 72 + lane] * enS[t]);
      }
      *(uint4*)&kT_b[lane * 72 + t8 * 8] = pt.u;
    }
  }

  // ---- phase 4: forward substitution; wave0: U0 (lane=e), wave1: W (lane=d) ----
  {
    float u[64];
    if (w == 0) {
#pragma unroll
      for (int j = 0; j < 64; j++) u[j] = beS[j] * vS[j * 64 + lane];
    } else {
#pragma unroll
      for (int j = 0; j < 64; j++) u[j] = beS[j] * expf(lgS[j]) * (float)k_b[j * 72 + lane];
    }
    __bf16* dst = (w == 0) ? U0T : WT;
#pragma unroll
    for (int j = 0; j < 64; j++) {
      dst[lane * 72 + j] = (__bf16)u[j];
      float uj = u[j];
#pragma unroll
      for (int g = (j >> 4); g < 4; g++) {
#pragma unroll
        for (int q4 = 0; q4 < 4; q4++) {
          const float4 m4 = *(const float4*)&MTf[j * 68 + g * 16 + q4 * 4];
          u[g * 16 + q4 * 4 + 0] -= m4.x * uj;
          u[g * 16 + q4 * 4 + 1] -= m4.y * uj;
          u[g * 16 + q4 * 4 + 2] -= m4.z * uj;
          u[g * 16 + q4 * 4 + 3] -= m4.w * uj;
        }
      }
    }
  }
  __syncthreads();

  // ---- phase 5: output products ----
  size_t cb = (size_t)bid * 4096;
  if (w == 0) {
    // BcT[e][d] = sum_s U0T[e][s] K''T[d][s];  Ac[d][d'] = sum_s K''T[d][s] WT[d'][s]
#pragma unroll
    for (int mi = 0; mi < 4; mi++)
#pragma unroll
      for (int ni = 0; ni < 4; ni++) {
        f32x4 ab = {0.f, 0.f, 0.f, 0.f};
        f32x4 aa = {0.f, 0.f, 0.f, 0.f};
#pragma unroll
        for (int ks = 0; ks < 2; ks++) {
          int aoff = (mi * 16 + (lane & 15)) * 72 + ks * 32 + (lane >> 4) * 8;
          int boff = (ni * 16 + (lane & 15)) * 72 + ks * 32 + (lane >> 4) * 8;
          bf16x8 fu = *(const bf16x8*)&U0T[aoff];
          bf16x8 fkm = *(const bf16x8*)&kT_b[aoff];
          bf16x8 fkn = *(const bf16x8*)&kT_b[boff];
          bf16x8 fw = *(const bf16x8*)&WT[boff];
          ab = __builtin_amdgcn_mfma_f32_16x16x32_bf16(fu, fkn, ab, 0, 0, 0);
          aa = __builtin_amdgcn_mfma_f32_16x16x32_bf16(fkm, fw, aa, 0, 0, 0);
        }
#pragma unroll
        for (int r = 0; r < 4; r++) {
          int row = mi * 16 + (lane >> 4) * 4 + r;
          int col = ni * 16 + (lane & 15);
          BcTF[cb + row * 64 + col] = ab[r];
          AcF[cb + row * 64 + col] = aa[r];
        }
      }
  } else {
    // O1[t][e] = C@U0 + aw*v;  Qeff[t][d] = e^{pv_t} q[t][d] - (C@W)[t][d]
#pragma unroll
    for (int mi = 0; mi < 4; mi++)
#pragma unroll
      for (int ni = 0; ni < 4; ni++) {
        f32x4 ao = {0.f, 0.f, 0.f, 0.f};
        f32x4 ac = {0.f, 0.f, 0.f, 0.f};
#pragma unroll
        for (int ks = 0; ks < 2; ks++) {
          int aoff = (mi * 16 + (lane & 15)) * 72 + ks * 32 + (lane >> 4) * 8;
          int boff = (ni * 16 + (lane & 15)) * 72 + ks * 32 + (lane >> 4) * 8;
          bf16x8 fc = *(const bf16x8*)&C_b[aoff];
          bf16x8 fu = *(const bf16x8*)&U0T[boff];
          bf16x8 fw = *(const bf16x8*)&WT[boff];
          ao = __builtin_amdgcn_mfma_f32_16x16x32_bf16(fc, fu, ao, 0, 0, 0);
          ac = __builtin_amdgcn_mfma_f32_16x16x32_bf16(fc, fw, ac, 0, 0, 0);
        }
#pragma unroll
        for (int r = 0; r < 4; r++) {
          int t = mi * 16 + (lane >> 4) * 4 + r;
          int col = ni * 16 + (lane & 15);
          O1[(size_t)bh * 65536 + (size_t)(t0 + t) * 64 + col] =
              ao[r] + awS[t] * vS[t * 64 + col];
          QeffF[cb + t * 64 + col] = expf(pvS[t]) * (float)q_b[t * 72 + col] - ac[r];
        }
      }
  }
}

// ---------------------------------------------------------------------------
// K8b: serial state carry. Grid 32 (bh), 4 waves. Per chunk c:
//   write S0T (state entering chunk) to global, then
//   S^T <- gC*S^T - (S^T Ac^T) + BcT   (S hi/lo split for fp32 fidelity)
// ---------------------------------------------------------------------------
__global__ __launch_bounds__(256) void k_scanB(
    const float* __restrict__ AcF, const float* __restrict__ BcTF,
    const float* __restrict__ gcF, float* __restrict__ S0TF) {
  const int bh = blockIdx.x;
  const int tid = threadIdx.x;
  const int w = tid >> 6, lane = tid & 63;
  const int er = tid >> 2, seg = (tid & 3) * 16;
  __shared__ float STf[64 * 68];
  __shared__ __bf16 Sh[64 * 72], Sl[64 * 72], Ac_b[64 * 72];
#pragma unroll
  for (int i = 0; i < 4; i++)
    *(float4*)&STf[er * 68 + seg + i * 4] = make_float4(0.f, 0.f, 0.f, 0.f);
  __syncthreads();

  for (int c = 0; c < 16; c++) {
    size_t cb = (size_t)(bh * 16 + c) * 4096;
    // emit S0T + build hi/lo copies; stage Ac -> bf16
#pragma unroll
    for (int i = 0; i < 4; i++) {
      float4 s = *(const float4*)&STf[er * 68 + seg + i * 4];
      *(float4*)&S0TF[cb + er * 64 + seg + i * 4] = s;
      union { __bf16 h[4]; unsigned long long u; } ph, pl;
      float sv[4] = {s.x, s.y, s.z, s.w};
#pragma unroll
      for (int q = 0; q < 4; q++) {
        __bf16 hv = (__bf16)sv[q];
        ph.h[q] = hv;
        pl.h[q] = (__bf16)(sv[q] - (float)hv);
      }
      *(unsigned long long*)&Sh[er * 72 + seg + i * 4] = ph.u;
      *(unsigned long long*)&Sl[er * 72 + seg + i * 4] = pl.u;
    }
#pragma unroll
    for (int i = 0; i < 4; i++) {
      float4 a = *(const float4*)&AcF[cb + er * 64 + seg + i * 4];
      union { __bf16 h[4]; unsigned long long u; } pa;
      pa.h[0] = (__bf16)a.x; pa.h[1] = (__bf16)a.y;
      pa.h[2] = (__bf16)a.z; pa.h[3] = (__bf16)a.w;
      *(unsigned long long*)&Ac_b[er * 72 + seg + i * 4] = pa.u;
    }
    float gC = gcF[bh * 16 + c];
    __syncthreads();

    f32x4 acc[4];
#pragma unroll
    for (int ni = 0; ni < 4; ni++) {
      acc[ni] = (f32x4){0.f, 0.f, 0.f, 0.f};
#pragma unroll
      for (int ks = 0; ks < 2; ks++) {
        int aoff = (w * 16 + (lane & 15)) * 72 + ks * 32 + (lane >> 4) * 8;
        int boff = (ni * 16 + (lane & 15)) * 72 + ks * 32 + (lane >> 4) * 8;
        bf16x8 ah = *(const bf16x8*)&Sh[aoff];
        bf16x8 al = *(const bf16x8*)&Sl[aoff];
        bf16x8 bb = *(const bf16x8*)&Ac_b[boff];
        acc[ni] = __builtin_amdgcn_mfma_f32_16x16x32_bf16(ah, bb, acc[ni], 0, 0, 0);
        acc[ni] = __builtin_amdgcn_mfma_f32_16x16x32_bf16(al, bb, acc[ni], 0, 0, 0);
      }
    }
#pragma unroll
    for (int ni = 0; ni < 4; ni++)
#pragma unroll
      for (int r = 0; r < 4; r++) {
        int e = w * 16 + (lane >> 4) * 4 + r;
        int d = ni * 16 + (lane & 15);
        float bct = BcTF[cb + e * 64 + d];
        STf[e * 68 + d] = gC * STf[e * 68 + d] - acc[ni][r] + bct;
      }
    __syncthreads();
  }
}

// ---------------------------------------------------------------------------
// K8c: O += Qeff @ S0 (hi/lo S0). Grid 512 (bh*16+c), 4 waves. RMW obuf.
// ---------------------------------------------------------------------------
__global__ __launch_bounds__(256) void k_scanC(
    const float* __restrict__ S0TF, const float* __restrict__ QeffF,
    float* __restrict__ obuf) {
  const int bid = blockIdx.x;
  const int bh = bid >> 4, c = bid & 15, t0 = c * 64;
  const int tid = threadIdx.x;
  const int w = tid >> 6, lane = tid & 63;
  const int er = tid >> 2, seg = (tid & 3) * 16;
  size_t cb = (size_t)bid * 4096;
  __shared__ __bf16 Sh[64 * 72], Sl[64 * 72], Qb[64 * 72];
#pragma unroll
  for (int i = 0; i < 4; i++) {
    float4 s = *(const float4*)&S0TF[cb + er * 64 + seg + i * 4];
    union { __bf16 h[4]; unsigned long long u; } ph, pl;
    float sv[4] = {s.x, s.y, s.z, s.w};
#pragma unroll
    for (int q = 0; q < 4; q++) {
      __bf16 hv = (__bf16)sv[q];
      ph.h[q] = hv;
      pl.h[q] = (__bf16)(sv[q] - (float)hv);
    }
    *(unsigned long long*)&Sh[er * 72 + seg + i * 4] = ph.u;
    *(unsigned long long*)&Sl[er * 72 + seg + i * 4] = pl.u;
    float4 qq = *(const float4*)&QeffF[cb + er * 64 + seg + i * 4];
    union { __bf16 h[4]; unsigned long long u; } pq;
    pq.h[0] = (__bf16)qq.x; pq.h[1] = (__bf16)qq.y;
    pq.h[2] = (__bf16)qq.z; pq.h[3] = (__bf16)qq.w;
    *(unsigned long long*)&Qb[er * 72 + seg + i * 4] = pq.u;
  }
  __syncthreads();
#pragma unroll
  for (int ni = 0; ni < 4; ni++) {
    f32x4 acc = {0.f, 0.f, 0.f, 0.f};
#pragma unroll
    for (int ks = 0; ks < 2; ks++) {
      int aoff = (w * 16 + (lane & 15)) * 72 + ks * 32 + (lane >> 4) * 8;
      int boff = (ni * 16 + (lane & 15)) * 72 + ks * 32 + (lane >> 4) * 8;
      bf16x8 fq = *(const bf16x8*)&Qb[aoff];
      bf16x8 sh = *(const bf16x8*)&Sh[boff];
      bf16x8 sl = *(const bf16x8*)&Sl[boff];
      acc = __builtin_amdgcn_mfma_f32_16x16x32_bf16(fq, sh, acc, 0, 0, 0);
      acc = __builtin_amdgcn_mfma_f32_16x16x32_bf16(fq, sl, acc, 0, 0, 0);
    }
#pragma unroll
    for (int r = 0; r < 4; r++) {
      int t = w * 16 + (lane >> 4) * 4 + r;
      int e = ni * 16 + (lane & 15);
      size_t oi = (size_t)bh * 65536 + (size_t)(t0 + t) * 64 + e;
      obuf[oi] += acc[r];
    }
  }
}

// ---------------------------------------------------------------------------
// K9: output RMS-norm + gate, writes bf16 hi/lo pair
// ---------------------------------------------------------------------------
__global__ __launch_bounds__(256) void k_outnorm(
    const float* __restrict__ obuf, const float* __restrict__ g,
    const float* __restrict__ onw, __bf16* __restrict__ rh,
    __bf16* __restrict__ rl) {
  int widx = blockIdx.x * 4 + (threadIdx.x >> 6);
  int lane = threadIdx.x & 63;
  int h = widx & 15, bt = widx >> 4;
  int t = bt & 1023, b = bt >> 10;
  float ov = obuf[(((size_t)(b * 16 + h)) * 1024 + t) * 64 + lane];
  float ss = ov * ov;
#pragma unroll
  for (int m = 1; m < 64; m <<= 1) ss += __shfl_xor(ss, m);
  float on = ov * rsqrtf(ss * (1.f / 64.f) + 1e-6f) * onw[lane];
  float sil = on / (1.f + expf(-on));
  float gv = g[(size_t)bt * 1024 + h * 64 + lane];
  float r = gv * sil;
  __bf16 hv = (__bf16)r;
  rh[(size_t)bt * 1024 + h * 64 + lane] = hv;
  rl[(size_t)bt * 1024 + h * 64 + lane] = (__bf16)(r - (float)hv);
}

// ---------------------------------------------------------------------------
extern "C" void kernel_launch(void* const* d_in, const int* in_sizes, int n_in,
                              void* d_out, int out_size, void* d_ws, size_t ws_size,
                              hipStream_t stream) {
  (void)in_sizes; (void)n_in; (void)out_size; (void)ws_size;
  const float* x    = (const float*)d_in[0];
  const float* Wq   = (const float*)d_in[1];
  const float* Wk   = (const float*)d_in[2];
  const float* Wv   = (const float*)d_in[3];
  const float* Wg   = (const float*)d_in[4];
  const float* Wo   = (const float*)d_in[5];
  const float* bw   = (const float*)d_in[6];
  const float* bb   = (const float*)d_in[7];
  const float* gkw  = (const float*)d_in[8];
  const float* gkb  = (const float*)d_in[9];
  const float* qcw  = (const float*)d_in[10];
  const float* qcb  = (const float*)d_in[11];
  const float* kcw  = (const float*)d_in[12];
  const float* kcb  = (const float*)d_in[13];
  const float* vcw  = (const float*)d_in[14];
  const float* vcb  = (const float*)d_in[15];
  const float* A_log= (const float*)d_in[16];
  const float* Dp   = (const float*)d_in[17];
  const float* dtb  = (const float*)d_in[18];
  const float* onw  = (const float*)d_in[19];

  char* ws = (char*)d_ws;
  const size_t MB = 1024 * 1024;
  // 0..8: xb hi/lo -> qc (conv out) -> AcF (scan) -> r_h/r_l (outnorm out)
  __bf16* xb_h = (__bf16*)(ws + 0);
  __bf16* xb_l = (__bf16*)(ws + 4 * MB);
  // 8..24: Wq/Wk/Wv/Wg hi+lo -> kc (8..16), vr (16..24); 8..16 -> BcTF (scan)
  __bf16* Wq_h = (__bf16*)(ws + 8 * MB);
  __bf16* Wq_l = (__bf16*)(ws + 10 * MB);
  __bf16* Wk_h = (__bf16*)(ws + 12 * MB);
  __bf16* Wk_l = (__bf16*)(ws + 14 * MB);
  __bf16* Wv_h = (__bf16*)(ws + 16 * MB);
  __bf16* Wv_l = (__bf16*)(ws + 18 * MB);
  __bf16* Wg_h = (__bf16*)(ws + 20 * MB);
  __bf16* Wg_l = (__bf16*)(ws + 22 * MB);
  // 24..28: Wo hi/lo (live to end)
  __bf16* Wo_h = (__bf16*)(ws + 24 * MB);
  __bf16* Wo_l = (__bf16*)(ws + 26 * MB);
  // 28..60: fp32 intermediates
  float* q_pre = (float*)(ws + 28 * MB);   // -> qrb (scanA in) -> S0TF (scanB out)
  float* k_pre = (float*)(ws + 36 * MB);   // -> krb
  float* v_pre = (float*)(ws + 44 * MB);   // -> obuf (O1 by scanA, RMW scanC)
  float* g_buf = (float*)(ws + 52 * MB);
  float* qc    = (float*)(ws + 0);
  float* kc    = (float*)(ws + 8 * MB);
  float* vr    = (float*)(ws + 16 * MB);
  float* qrb   = q_pre;
  float* krb   = k_pre;
  float* obuf  = v_pre;
  __bf16* r_h  = (__bf16*)(ws + 0);
  __bf16* r_l  = (__bf16*)(ws + 4 * MB);
  // scan buffers
  float* AcF   = (float*)(ws + 0);         // 8MB (qc dead after ropenorm)
  float* BcTF  = (float*)(ws + 8 * MB);    // 8MB (kc dead after ropenorm)
  float* S0TF  = (float*)(ws + 28 * MB);   // 8MB (qrb dead after scanA)
  float* QeffF = (float*)(ws + 61 * MB);   // 8MB (61..69, within proven 71MB)
  float* gcF   = (float*)(ws + 69 * MB);   // 2KB
  // 60..61: small buffers
  float* alphaB = (float*)(ws + 60 * MB);
  float* betaB  = (float*)(ws + 60 * MB + 128 * 1024);
  float4* aux   = (float4*)(ws + 60 * MB + 256 * 1024);
  float* ct     = (float*)(ws + 60 * MB + 768 * 1024);
  float* st     = (float*)(ws + 60 * MB + 896 * 1024);
  float* out    = (float*)d_out;

  k_tobf16_split<<<1024, 256, 0, stream>>>(x, xb_h, xb_l, 262144);
  k_transp_split<<<dim3(16, 16, 5), 256, 0, stream>>>(
      Wq, Wk, Wv, Wg, Wo,
      Wq_h, Wk_h, Wv_h, Wg_h, Wo_h,
      Wq_l, Wk_l, Wv_l, Wg_l, Wo_l);
  k_rope_table<<<128, 256, 0, stream>>>(ct, st);
  k_gates<<<2048, 256, 0, stream>>>(x, bw, bb, gkw, gkb, A_log, dtb, alphaB, betaB);
  k_gemm3<<<dim3(8, 16, 4), 256, 0, stream>>>(
      xb_h, xb_l,
      Wq_h, Wk_h, Wv_h, Wg_h,
      Wq_l, Wk_l, Wv_l, Wg_l,
      q_pre, k_pre, v_pre, g_buf, 1024, 1024);
  k_conv<<<dim3(8192, 3), 256, 0, stream>>>(q_pre, k_pre, v_pre, qcw, kcw, vcw,
                                            qcb, kcb, vcb, qc, kc, vr);
  k_ropenorm<<<8192, 256, 0, stream>>>(qc, kc, ct, st, alphaB, betaB, Dp, qrb, krb, aux);
  // chunked WY scan: parallel chunk prep -> serial affine carry -> parallel O
  k_scanA<<<512, 128, 0, stream>>>(qrb, krb, vr, aux, obuf, AcF, BcTF, QeffF, gcF);
  k_scanB<<<32, 256, 0, stream>>>(AcF, BcTF, gcF, S0TF);
  k_scanC<<<512, 256, 0, stream>>>(S0TF, QeffF, obuf);
  k_outnorm<<<8192, 256, 0, stream>>>(obuf, g_buf, onw, r_h, r_l);
  k_gemm3<<<dim3(8, 16, 1), 256, 0, stream>>>(
      r_h, r_l,
      Wo_h, Wo_h, Wo_h, Wo_h,
      Wo_l, Wo_l, Wo_l, Wo_l,
      out, out, out, out, 1024, 1024);
}

// Round 6
// 331.665 us; speedup vs baseline: 5.1578x; 1.0363x over previous
//
#include <hip/hip_runtime.h>
#include <hip/hip_bf16.h>
#include <cstdint>

// Problem constants
#define T_LEN 1024
#define HIDN  1024
#define NH    16
#define DHD   64

typedef __bf16 bf16x8 __attribute__((ext_vector_type(8)));
typedef float  f32x4  __attribute__((ext_vector_type(4)));

__device__ inline void split8(float4 x0, float4 x1, uint4& hi, uint4& lo) {
  union { __bf16 h[8]; uint4 u; } ph, pl;
  float v[8] = {x0.x, x0.y, x0.z, x0.w, x1.x, x1.y, x1.z, x1.w};
#pragma unroll
  for (int j = 0; j < 8; j++) {
    __bf16 h = (__bf16)v[j];
    ph.h[j] = h;
    pl.h[j] = (__bf16)(v[j] - (float)h);
  }
  hi = ph.u; lo = pl.u;
}

// ---------------------------------------------------------------------------
// K2: transpose 1024x1024 f32 W[k][n] -> bf16 hi/lo Wt[n][k] (5 weights via z)
// ---------------------------------------------------------------------------
__global__ __launch_bounds__(256) void k_transp_split(
    const float* __restrict__ W0, const float* __restrict__ W1,
    const float* __restrict__ W2, const float* __restrict__ W3,
    const float* __restrict__ W4,
    __bf16* __restrict__ H0, __bf16* __restrict__ H1, __bf16* __restrict__ H2,
    __bf16* __restrict__ H3, __bf16* __restrict__ H4,
    __bf16* __restrict__ L0, __bf16* __restrict__ L1, __bf16* __restrict__ L2,
    __bf16* __restrict__ L3, __bf16* __restrict__ L4) {
  const float* W; __bf16* Th; __bf16* Tl;
  switch (blockIdx.z) {
    case 0: W = W0; Th = H0; Tl = L0; break;
    case 1: W = W1; Th = H1; Tl = L1; break;
    case 2: W = W2; Th = H2; Tl = L2; break;
    case 3: W = W3; Th = H3; Tl = L3; break;
    default: W = W4; Th = H4; Tl = L4; break;
  }
  __shared__ float tile[64][65];
  int tid = threadIdx.x;
  int r0 = tid >> 4;          // 0..15
  int c0 = (tid & 15) * 4;    // 0..60
  int kbase = blockIdx.y * 64, nbase = blockIdx.x * 64;
#pragma unroll
  for (int rr = 0; rr < 4; rr++) {
    int r = r0 + rr * 16;
    float4 v = *(const float4*)(W + (size_t)(kbase + r) * 1024 + nbase + c0);
    tile[r][c0 + 0] = v.x; tile[r][c0 + 1] = v.y;
    tile[r][c0 + 2] = v.z; tile[r][c0 + 3] = v.w;
  }
  __syncthreads();
#pragma unroll
  for (int rr = 0; rr < 4; rr++) {
    int n = r0 + rr * 16;
    union { __bf16 h[4]; unsigned long long u; } ph, pl;
#pragma unroll
    for (int j = 0; j < 4; j++) {
      float v = tile[c0 + j][n];
      __bf16 h = (__bf16)v;
      ph.h[j] = h;
      pl.h[j] = (__bf16)(v - (float)h);
    }
    *(unsigned long long*)(Th + (size_t)(nbase + n) * 1024 + kbase + c0) = ph.u;
    *(unsigned long long*)(Tl + (size_t)(nbase + n) * 1024 + kbase + c0) = pl.u;
  }
}

// ---------------------------------------------------------------------------
// K3: split-precision GEMM, A fp32 (inline hi/lo split), B pre-split bf16.
// C = Ah*Bh + Al*Bh + Ah*Bl. 128x128 tile, BK=32, 4 waves.
// ---------------------------------------------------------------------------
#define LDT 40
__global__ __launch_bounds__(256) void k_gemm3f(
    const float* __restrict__ Af,
    const __bf16* __restrict__ Bh0, const __bf16* __restrict__ Bh1,
    const __bf16* __restrict__ Bh2, const __bf16* __restrict__ Bh3,
    const __bf16* __restrict__ Bl0, const __bf16* __restrict__ Bl1,
    const __bf16* __restrict__ Bl2, const __bf16* __restrict__ Bl3,
    float* __restrict__ C0, float* __restrict__ C1,
    float* __restrict__ C2, float* __restrict__ C3,
    int Kdim, int Ncols) {
  const __bf16* Bh; const __bf16* Bl; float* C;
  switch (blockIdx.z) {
    case 0: Bh = Bh0; Bl = Bl0; C = C0; break;
    case 1: Bh = Bh1; Bl = Bl1; C = C1; break;
    case 2: Bh = Bh2; Bl = Bl2; C = C2; break;
    default: Bh = Bh3; Bl = Bl3; C = C3; break;
  }
  __shared__ __bf16 Ash[128 * LDT];
  __shared__ __bf16 Asl[128 * LDT];
  __shared__ __bf16 Bsh[128 * LDT];
  __shared__ __bf16 Bsl[128 * LDT];
  const int tid = threadIdx.x;
  const int lane = tid & 63;
  const int wave = tid >> 6;
  const int wr = wave >> 1, wc = wave & 1;
  const int rowA0 = blockIdx.y * 128;
  const int colB0 = blockIdx.x * 128;
  const int sseg = tid & 3;
  const int srow0 = tid >> 2;
  const int srow1 = srow0 + 64;

  f32x4 acc[4][4] = {};

  for (int k0 = 0; k0 < Kdim; k0 += 32) {
    size_t a0 = (size_t)(rowA0 + srow0) * Kdim + k0 + sseg * 8;
    size_t a1 = (size_t)(rowA0 + srow1) * Kdim + k0 + sseg * 8;
    size_t b0 = (size_t)(colB0 + srow0) * Kdim + k0 + sseg * 8;
    size_t b1 = (size_t)(colB0 + srow1) * Kdim + k0 + sseg * 8;
    float4 a00 = *(const float4*)(Af + a0);
    float4 a01 = *(const float4*)(Af + a0 + 4);
    float4 a10 = *(const float4*)(Af + a1);
    float4 a11 = *(const float4*)(Af + a1 + 4);
    uint4 rbh0 = *(const uint4*)(Bh + b0);
    uint4 rbh1 = *(const uint4*)(Bh + b1);
    uint4 rbl0 = *(const uint4*)(Bl + b0);
    uint4 rbl1 = *(const uint4*)(Bl + b1);
    uint4 rah0, ral0, rah1, ral1;
    split8(a00, a01, rah0, ral0);
    split8(a10, a11, rah1, ral1);
    __syncthreads();
    *(uint4*)&Ash[srow0 * LDT + sseg * 8] = rah0;
    *(uint4*)&Ash[srow1 * LDT + sseg * 8] = rah1;
    *(uint4*)&Asl[srow0 * LDT + sseg * 8] = ral0;
    *(uint4*)&Asl[srow1 * LDT + sseg * 8] = ral1;
    *(uint4*)&Bsh[srow0 * LDT + sseg * 8] = rbh0;
    *(uint4*)&Bsh[srow1 * LDT + sseg * 8] = rbh1;
    *(uint4*)&Bsl[srow0 * LDT + sseg * 8] = rbl0;
    *(uint4*)&Bsl[srow1 * LDT + sseg * 8] = rbl1;
    __syncthreads();
    bf16x8 afh[4], afl[4], bfh[4], bfl[4];
#pragma unroll
    for (int mi = 0; mi < 4; mi++) {
      int off = (wr * 64 + mi * 16 + (lane & 15)) * LDT + (lane >> 4) * 8;
      afh[mi] = *(const bf16x8*)&Ash[off];
      afl[mi] = *(const bf16x8*)&Asl[off];
    }
#pragma unroll
    for (int ni = 0; ni < 4; ni++) {
      int off = (wc * 64 + ni * 16 + (lane & 15)) * LDT + (lane >> 4) * 8;
      bfh[ni] = *(const bf16x8*)&Bsh[off];
      bfl[ni] = *(const bf16x8*)&Bsl[off];
    }
#pragma unroll
    for (int mi = 0; mi < 4; mi++)
#pragma unroll
      for (int ni = 0; ni < 4; ni++) {
        acc[mi][ni] = __builtin_amdgcn_mfma_f32_16x16x32_bf16(afh[mi], bfh[ni], acc[mi][ni], 0, 0, 0);
        acc[mi][ni] = __builtin_amdgcn_mfma_f32_16x16x32_bf16(afl[mi], bfh[ni], acc[mi][ni], 0, 0, 0);
        acc[mi][ni] = __builtin_amdgcn_mfma_f32_16x16x32_bf16(afh[mi], bfl[ni], acc[mi][ni], 0, 0, 0);
      }
  }
#pragma unroll
  for (int mi = 0; mi < 4; mi++)
#pragma unroll
    for (int ni = 0; ni < 4; ni++) {
      int col = colB0 + wc * 64 + ni * 16 + (lane & 15);
#pragma unroll
      for (int r = 0; r < 4; r++) {
        int row = rowA0 + wr * 64 + mi * 16 + (lane >> 4) * 4 + r;
        C[(size_t)row * Ncols + col] = acc[mi][ni][r];
      }
    }
}

// ---------------------------------------------------------------------------
// K4: gates
// ---------------------------------------------------------------------------
__global__ __launch_bounds__(256) void k_gates(
    const float* __restrict__ x, const float* __restrict__ bw,
    const float* __restrict__ bb, const float* __restrict__ gkw,
    const float* __restrict__ gkb, const float* __restrict__ A_log,
    const float* __restrict__ dt_bias,
    float* __restrict__ alphaB, float* __restrict__ betaB) {
  const int bt = blockIdx.x;
  const int tid = threadIdx.x;
  const int h = tid & 15;
  const int chunk = tid >> 4;
  const float* xr = x + (size_t)bt * HIDN;
  float d1 = 0.f, d2 = 0.f;
#pragma unroll 8
  for (int j = 0; j < 64; j++) {
    int k = chunk * 64 + j;
    float xv = xr[k];
    d1 += xv * bw[k * 16 + h];
    d2 += xv * gkw[k * 16 + h];
  }
  __shared__ float p1[16][16], p2[16][16];
  p1[chunk][h] = d1; p2[chunk][h] = d2;
  __syncthreads();
  if (tid < 16) {
    float s1 = 0.f, s2 = 0.f;
#pragma unroll
    for (int c = 0; c < 16; c++) { s1 += p1[c][tid]; s2 += p2[c][tid]; }
    float beta = 1.f / (1.f + expf(-(s1 + bb[tid])));
    float z = s2 + gkb[tid] + dt_bias[tid];
    float sp = fmaxf(z, 0.f) + log1pf(expf(-fabsf(z)));
    float alpha = expf(-expf(A_log[tid]) * sp);
    alphaB[(size_t)bt * 16 + tid] = alpha;
    betaB[(size_t)bt * 16 + tid] = beta;
  }
}

// ---------------------------------------------------------------------------
// K_CRA: fused causal dwconv(K=4)+SiLU -> RoPE -> L2 norm -> aux pack.
// One wave per (bt,h); lane = channel-within-head d.
// Outputs q,k (roped+normed) and v in scan layout [bh][t][d]; aux f4.
// ---------------------------------------------------------------------------
__global__ __launch_bounds__(256) void k_cra(
    const float* __restrict__ qp, const float* __restrict__ kp,
    const float* __restrict__ vp,
    const float* __restrict__ qcw, const float* __restrict__ qcb,
    const float* __restrict__ kcw, const float* __restrict__ kcb,
    const float* __restrict__ vcw, const float* __restrict__ vcb,
    const float* __restrict__ alphaB, const float* __restrict__ betaB,
    const float* __restrict__ Dp,
    float* __restrict__ qr, float* __restrict__ kr, float* __restrict__ vr,
    float4* __restrict__ aux) {
  int widx = blockIdx.x * 4 + (threadIdx.x >> 6);
  int lane = threadIdx.x & 63;
  int h = widx & 15;
  int bt = widx >> 4;
  int t = bt & 1023, b = bt >> 10;
  int c = h * 64 + lane;
  size_t colbase = ((size_t)b * 1024) * 1024 + c;

  // conv + silu for q, k, v
  float4 wq = *(const float4*)(qcw + (size_t)c * 4);
  float4 wk = *(const float4*)(kcw + (size_t)c * 4);
  float4 wv = *(const float4*)(vcw + (size_t)c * 4);
  float aq = qcb[c], ak = kcb[c], av = vcb[c];
  {
    float x0 = qp[colbase + (size_t)t * 1024];
    float y0 = kp[colbase + (size_t)t * 1024];
    float z0 = vp[colbase + (size_t)t * 1024];
    aq += wq.w * x0; ak += wk.w * y0; av += wv.w * z0;
    if (t >= 1) {
      float x1 = qp[colbase + (size_t)(t - 1) * 1024];
      float y1 = kp[colbase + (size_t)(t - 1) * 1024];
      float z1 = vp[colbase + (size_t)(t - 1) * 1024];
      aq += wq.z * x1; ak += wk.z * y1; av += wv.z * z1;
    }
    if (t >= 2) {
      float x2 = qp[colbase + (size_t)(t - 2) * 1024];
      float y2 = kp[colbase + (size_t)(t - 2) * 1024];
      float z2 = vp[colbase + (size_t)(t - 2) * 1024];
      aq += wq.y * x2; ak += wk.y * y2; av += wv.y * z2;
    }
    if (t >= 3) {
      float x3 = qp[colbase + (size_t)(t - 3) * 1024];
      float y3 = kp[colbase + (size_t)(t - 3) * 1024];
      float z3 = vp[colbase + (size_t)(t - 3) * 1024];
      aq += wq.x * x3; ak += wk.x * y3; av += wv.x * z3;
    }
  }
  float yq = aq / (1.f + expf(-aq));
  float yk = ak / (1.f + expf(-ak));
  float yv = av / (1.f + expf(-av));

  // rope: lane i<32 -> x1*c - x2*s ; i>=32 -> x1*s + x2*c  (pair 2i, 2i+1)
  int i = lane & 31;
  float fr = expf(-(float)(2 * (i & 15)) * (9.210340371976184f / 32.f));
  float ang = (float)t * fr;
  float cv = cosf(ang), sv = sinf(ang);
  float q1 = __shfl(yq, 2 * i), q2 = __shfl(yq, 2 * i + 1);
  float k1 = __shfl(yk, 2 * i), k2 = __shfl(yk, 2 * i + 1);
  float qo = (lane < 32) ? (q1 * cv - q2 * sv) : (q1 * sv + q2 * cv);
  float ko = (lane < 32) ? (k1 * cv - k2 * sv) : (k1 * sv + k2 * cv);

  // L2 norm + aux
  float qs = qo * qo, ks2 = ko * ko;
#pragma unroll
  for (int m = 1; m < 64; m <<= 1) { qs += __shfl_xor(qs, m); ks2 += __shfl_xor(ks2, m); }
  float qn = qo * rsqrtf(qs + 1e-6f);
  float kn = ko * rsqrtf(ks2 + 1e-6f);
  float dq = qn * kn;
#pragma unroll
  for (int m = 1; m < 64; m <<= 1) dq += __shfl_xor(dq, m);
  size_t obase = ((size_t)(b * 16 + h) * 1024 + t) * 64;
  qr[obase + lane] = qn;
  kr[obase + lane] = kn;
  vr[obase + lane] = yv;
  if (lane == 0) {
    float alpha = alphaB[(size_t)bt * 16 + h];
    float beta = betaB[(size_t)bt * 16 + h];
    aux[(size_t)(b * 16 + h) * 1024 + t] = make_float4(alpha, beta, alpha * beta, Dp[h] * dq);
  }
}

// ---------------------------------------------------------------------------
// K8a: WY-form scan, S0-independent per-chunk work (unchanged math).
// ---------------------------------------------------------------------------
__global__ __launch_bounds__(128) void k_scanA(
    const float* __restrict__ qr, const float* __restrict__ kr,
    const float* __restrict__ vr, const float4* __restrict__ aux,
    float* __restrict__ O1, float* __restrict__ AcF,
    float* __restrict__ BcTF, float* __restrict__ QeffF,
    float* __restrict__ gcF) {
  const int bid = blockIdx.x;
  const int bh = bid >> 4, c = bid & 15;
  const int t0 = c * 64;
  const int tid = threadIdx.x;
  const int w = tid >> 6, lane = tid & 63;
  const float* qB = qr + (size_t)bh * 65536 + (size_t)t0 * 64;
  const float* kB = kr + (size_t)bh * 65536 + (size_t)t0 * 64;
  const float* vB = vr + (size_t)bh * 65536 + (size_t)t0 * 64;
  const float4* auxB = aux + (size_t)bh * T_LEN + t0;

  __shared__ __bf16 q_b[64 * 72];
  __shared__ __bf16 k_b[64 * 72];
  __shared__ __bf16 kT_b[64 * 72];
  __shared__ __bf16 C_b[64 * 72];
  __shared__ __bf16 U0T[64 * 72];
  __shared__ __bf16 WT[64 * 72];
  __shared__ float  vS[64 * 64];
  __shared__ float  MTf[64 * 68];
  __shared__ float  lgS[64], pvS[64], beS[64], awS[64], enS[64];

  if (w == 0) {
    float4 a4 = auxB[lane];
    float lg = logf(a4.x);
#pragma unroll
    for (int off = 1; off < 64; off <<= 1) {
      float tv = __shfl_up(lg, off);
      if (lane >= off) lg += tv;
    }
    float pv = __shfl_up(lg, 1);
    if (lane == 0) pv = 0.f;
    float lgTot = __shfl(lg, 63);
    lgS[lane] = lg; pvS[lane] = pv; beS[lane] = a4.y; awS[lane] = a4.w;
    enS[lane] = expf(lgTot - lg);
    if (lane == 0) gcF[bid] = expf(lgTot);
  }
#pragma unroll
  for (int p = 0; p < 4; p++) {
    int s = p * 128 + tid;
    int row = s >> 3, col8 = s & 7;
    const float* gq = qB + (size_t)row * 64 + col8 * 8;
    const float* gk = kB + (size_t)row * 64 + col8 * 8;
    const float* gv = vB + (size_t)row * 64 + col8 * 8;
    float4 q0 = *(const float4*)gq, q1 = *(const float4*)(gq + 4);
    float4 k0 = *(const float4*)gk, k1 = *(const float4*)(gk + 4);
    float4 v0 = *(const float4*)gv, v1 = *(const float4*)(gv + 4);
    union { __bf16 h[8]; uint4 u; } pq, pk;
    pq.h[0] = (__bf16)q0.x; pq.h[1] = (__bf16)q0.y; pq.h[2] = (__bf16)q0.z; pq.h[3] = (__bf16)q0.w;
    pq.h[4] = (__bf16)q1.x; pq.h[5] = (__bf16)q1.y; pq.h[6] = (__bf16)q1.z; pq.h[7] = (__bf16)q1.w;
    pk.h[0] = (__bf16)k0.x; pk.h[1] = (__bf16)k0.y; pk.h[2] = (__bf16)k0.z; pk.h[3] = (__bf16)k0.w;
    pk.h[4] = (__bf16)k1.x; pk.h[5] = (__bf16)k1.y; pk.h[6] = (__bf16)k1.z; pk.h[7] = (__bf16)k1.w;
    *(uint4*)&q_b[row * 72 + col8 * 8] = pq.u;
    *(uint4*)&k_b[row * 72 + col8 * 8] = pk.u;
    *(float4*)&vS[row * 64 + col8 * 8] = v0;
    *(float4*)&vS[row * 64 + col8 * 8 + 4] = v1;
  }
  __syncthreads();

#pragma unroll
  for (int mm = 0; mm < 2; mm++) {
    int mi = w * 2 + mm;
#pragma unroll
    for (int ni = 0; ni < 4; ni++) {
      f32x4 akk = {0.f, 0.f, 0.f, 0.f};
      f32x4 aqk = {0.f, 0.f, 0.f, 0.f};
#pragma unroll
      for (int ks = 0; ks < 2; ks++) {
        bf16x8 fa_k = *(const bf16x8*)&k_b[(mi * 16 + (lane & 15)) * 72 + ks * 32 + (lane >> 4) * 8];
        bf16x8 fa_q = *(const bf16x8*)&q_b[(mi * 16 + (lane & 15)) * 72 + ks * 32 + (lane >> 4) * 8];
        bf16x8 fb_k = *(const bf16x8*)&k_b[(ni * 16 + (lane & 15)) * 72 + ks * 32 + (lane >> 4) * 8];
        akk = __builtin_amdgcn_mfma_f32_16x16x32_bf16(fa_k, fb_k, akk, 0, 0, 0);
        aqk = __builtin_amdgcn_mfma_f32_16x16x32_bf16(fa_q, fb_k, aqk, 0, 0, 0);
      }
#pragma unroll
      for (int r = 0; r < 4; r++) {
        int row = mi * 16 + (lane >> 4) * 4 + r;
        int col = ni * 16 + (lane & 15);
        float mt = 0.f, cv = 0.f;
        if (row > col) {
          mt = beS[row] * expf(lgS[row] - lgS[col]) * akk[r];
          cv = expf(pvS[row] - lgS[col]) * aqk[r];
        }
        MTf[col * 68 + row] = mt;
        C_b[row * 72 + col] = (__bf16)cv;
      }
    }
  }
  __syncthreads();

  if (w == 1) {
#pragma unroll
    for (int t8 = 0; t8 < 8; t8++) {
      union { __bf16 h[8]; uint4 u; } pt;
#pragma unroll
      for (int q = 0; q < 8; q++) {
        int t = t8 * 8 + q;
        pt.h[q] = (__bf16)((float)k_b[t * 72 + lane] * enS[t]);
      }
      *(uint4*)&kT_b[lane * 72 + t8 * 8] = pt.u;
    }
  }

  {
    float u[64];
    if (w == 0) {
#pragma unroll
      for (int j = 0; j < 64; j++) u[j] = beS[j] * vS[j * 64 + lane];
    } else {
#pragma unroll
      for (int j = 0; j < 64; j++) u[j] = beS[j] * expf(lgS[j]) * (float)k_b[j * 72 + lane];
    }
    __bf16* dst = (w == 0) ? U0T : WT;
#pragma unroll
    for (int j = 0; j < 64; j++) {
      dst[lane * 72 + j] = (__bf16)u[j];
      float uj = u[j];
#pragma unroll
      for (int g = (j >> 4); g < 4; g++) {
#pragma unroll
        for (int q4 = 0; q4 < 4; q4++) {
          const float4 m4 = *(const float4*)&MTf[j * 68 + g * 16 + q4 * 4];
          u[g * 16 + q4 * 4 + 0] -= m4.x * uj;
          u[g * 16 + q4 * 4 + 1] -= m4.y * uj;
          u[g * 16 + q4 * 4 + 2] -= m4.z * uj;
          u[g * 16 + q4 * 4 + 3] -= m4.w * uj;
        }
      }
    }
  }
  __syncthreads();

  size_t cb = (size_t)bid * 4096;
  if (w == 0) {
#pragma unroll
    for (int mi = 0; mi < 4; mi++)
#pragma unroll
      for (int ni = 0; ni < 4; ni++) {
        f32x4 ab = {0.f, 0.f, 0.f, 0.f};
        f32x4 aa = {0.f, 0.f, 0.f, 0.f};
#pragma unroll
        for (int ks = 0; ks < 2; ks++) {
          int aoff = (mi * 16 + (lane & 15)) * 72 + ks * 32 + (lane >> 4) * 8;
          int boff = (ni * 16 + (lane & 15)) * 72 + ks * 32 + (lane >> 4) * 8;
          bf16x8 fu = *(const bf16x8*)&U0T[aoff];
          bf16x8 fkm = *(const bf16x8*)&kT_b[aoff];
          bf16x8 fkn = *(const bf16x8*)&kT_b[boff];
          bf16x8 fw = *(const bf16x8*)&WT[boff];
          ab = __builtin_amdgcn_mfma_f32_16x16x32_bf16(fu, fkn, ab, 0, 0, 0);
          aa = __builtin_amdgcn_mfma_f32_16x16x32_bf16(fkm, fw, aa, 0, 0, 0);
        }
#pragma unroll
        for (int r = 0; r < 4; r++) {
          int row = mi * 16 + (lane >> 4) * 4 + r;
          int col = ni * 16 + (lane & 15);
          BcTF[cb + row * 64 + col] = ab[r];
          AcF[cb + row * 64 + col] = aa[r];
        }
      }
  } else {
#pragma unroll
    for (int mi = 0; mi < 4; mi++)
#pragma unroll
      for (int ni = 0; ni < 4; ni++) {
        f32x4 ao = {0.f, 0.f, 0.f, 0.f};
        f32x4 ac = {0.f, 0.f, 0.f, 0.f};
#pragma unroll
        for (int ks = 0; ks < 2; ks++) {
          int aoff = (mi * 16 + (lane & 15)) * 72 + ks * 32 + (lane >> 4) * 8;
          int boff = (ni * 16 + (lane & 15)) * 72 + ks * 32 + (lane >> 4) * 8;
          bf16x8 fc = *(const bf16x8*)&C_b[aoff];
          bf16x8 fu = *(const bf16x8*)&U0T[boff];
          bf16x8 fw = *(const bf16x8*)&WT[boff];
          ao = __builtin_amdgcn_mfma_f32_16x16x32_bf16(fc, fu, ao, 0, 0, 0);
          ac = __builtin_amdgcn_mfma_f32_16x16x32_bf16(fc, fw, ac, 0, 0, 0);
        }
#pragma unroll
        for (int r = 0; r < 4; r++) {
          int t = mi * 16 + (lane >> 4) * 4 + r;
          int col = ni * 16 + (lane & 15);
          O1[(size_t)bh * 65536 + (size_t)(t0 + t) * 64 + col] =
              ao[r] + awS[t] * vS[t * 64 + col];
          QeffF[cb + t * 64 + col] = expf(pvS[t]) * (float)q_b[t * 72 + col] - ac[r];
        }
      }
  }
}

// ---------------------------------------------------------------------------
// K8b: serial state carry, software-pipelined global prefetch.
// ---------------------------------------------------------------------------
__global__ __launch_bounds__(256) void k_scanB(
    const float* __restrict__ AcF, const float* __restrict__ BcTF,
    const float* __restrict__ gcF, float* __restrict__ S0TF) {
  const int bh = blockIdx.x;
  const int tid = threadIdx.x;
  const int w = tid >> 6, lane = tid & 63;
  const int er = tid >> 2, seg = (tid & 3) * 16;
  __shared__ float STf[64 * 68];
  __shared__ __bf16 Sh[64 * 72], Sl[64 * 72], Ac_b[64 * 72];
#pragma unroll
  for (int i = 0; i < 4; i++)
    *(float4*)&STf[er * 68 + seg + i * 4] = make_float4(0.f, 0.f, 0.f, 0.f);
  __syncthreads();

  size_t cbase = (size_t)bh * 16 * 4096;
  // prologue: load chunk-0 Ac (stage layout) + BcT (epilogue layout)
  float4 acR[4];
  float bctR[16];
#pragma unroll
  for (int i = 0; i < 4; i++)
    acR[i] = *(const float4*)&AcF[cbase + er * 64 + seg + i * 4];
#pragma unroll
  for (int r = 0; r < 4; r++)
#pragma unroll
    for (int ni = 0; ni < 4; ni++) {
      int e = w * 16 + (lane >> 4) * 4 + r;
      int d = ni * 16 + (lane & 15);
      bctR[r * 4 + ni] = BcTF[cbase + e * 64 + d];
    }

  for (int c = 0; c < 16; c++) {
    size_t cb = cbase + (size_t)c * 4096;
    // stage S -> Sh/Sl, emit S0T, stage Ac regs -> LDS
#pragma unroll
    for (int i = 0; i < 4; i++) {
      float4 s = *(const float4*)&STf[er * 68 + seg + i * 4];
      *(float4*)&S0TF[cb + er * 64 + seg + i * 4] = s;
      union { __bf16 h[4]; unsigned long long u; } ph, pl, pa;
      float sv[4] = {s.x, s.y, s.z, s.w};
      float av[4] = {acR[i].x, acR[i].y, acR[i].z, acR[i].w};
#pragma unroll
      for (int q = 0; q < 4; q++) {
        __bf16 hv = (__bf16)sv[q];
        ph.h[q] = hv;
        pl.h[q] = (__bf16)(sv[q] - (float)hv);
        pa.h[q] = (__bf16)av[q];
      }
      *(unsigned long long*)&Sh[er * 72 + seg + i * 4] = ph.u;
      *(unsigned long long*)&Sl[er * 72 + seg + i * 4] = pl.u;
      *(unsigned long long*)&Ac_b[er * 72 + seg + i * 4] = pa.u;
    }
    float gC = gcF[bh * 16 + c];
    __syncthreads();

    // prefetch chunk c+1 (in flight across the MFMA block)
    float4 acN[4];
    float bctN[16];
    if (c < 15) {
      size_t nb = cb + 4096;
#pragma unroll
      for (int i = 0; i < 4; i++)
        acN[i] = *(const float4*)&AcF[nb + er * 64 + seg + i * 4];
#pragma unroll
      for (int r = 0; r < 4; r++)
#pragma unroll
        for (int ni = 0; ni < 4; ni++) {
          int e = w * 16 + (lane >> 4) * 4 + r;
          int d = ni * 16 + (lane & 15);
          bctN[r * 4 + ni] = BcTF[nb + e * 64 + d];
        }
    } else {
#pragma unroll
      for (int i = 0; i < 4; i++) acN[i] = acR[i];
#pragma unroll
      for (int j = 0; j < 16; j++) bctN[j] = bctR[j];
    }

    f32x4 acc[4];
#pragma unroll
    for (int ni = 0; ni < 4; ni++) {
      acc[ni] = (f32x4){0.f, 0.f, 0.f, 0.f};
#pragma unroll
      for (int ks = 0; ks < 2; ks++) {
        int aoff = (w * 16 + (lane & 15)) * 72 + ks * 32 + (lane >> 4) * 8;
        int boff = (ni * 16 + (lane & 15)) * 72 + ks * 32 + (lane >> 4) * 8;
        bf16x8 ah = *(const bf16x8*)&Sh[aoff];
        bf16x8 al = *(const bf16x8*)&Sl[aoff];
        bf16x8 bb = *(const bf16x8*)&Ac_b[boff];
        acc[ni] = __builtin_amdgcn_mfma_f32_16x16x32_bf16(ah, bb, acc[ni], 0, 0, 0);
        acc[ni] = __builtin_amdgcn_mfma_f32_16x16x32_bf16(al, bb, acc[ni], 0, 0, 0);
      }
    }
#pragma unroll
    for (int ni = 0; ni < 4; ni++)
#pragma unroll
      for (int r = 0; r < 4; r++) {
        int e = w * 16 + (lane >> 4) * 4 + r;
        int d = ni * 16 + (lane & 15);
        STf[e * 68 + d] = gC * STf[e * 68 + d] - acc[ni][r] + bctR[r * 4 + ni];
      }
    __syncthreads();
#pragma unroll
    for (int i = 0; i < 4; i++) acR[i] = acN[i];
#pragma unroll
    for (int j = 0; j < 16; j++) bctR[j] = bctN[j];
  }
}

// ---------------------------------------------------------------------------
// K8c+K9 fused: O = O1 + Qeff@S0, then RMS-norm + silu gate -> robuf fp32.
// ---------------------------------------------------------------------------
__global__ __launch_bounds__(256) void k_scanCn(
    const float* __restrict__ S0TF, const float* __restrict__ QeffF,
    const float* __restrict__ obuf, const float* __restrict__ g,
    const float* __restrict__ onw, float* __restrict__ robuf) {
  const int bid = blockIdx.x;
  const int bh = bid >> 4, c = bid & 15, t0c = c * 64;
  const int b = bh >> 4, h = bh & 15;
  const int tid = threadIdx.x;
  const int w = tid >> 6, lane = tid & 63;
  const int er = tid >> 2, seg = (tid & 3) * 16;
  size_t cb = (size_t)bid * 4096;
  __shared__ __bf16 Sh[64 * 72], Sl[64 * 72], Qb[64 * 72];
#pragma unroll
  for (int i = 0; i < 4; i++) {
    float4 s = *(const float4*)&S0TF[cb + er * 64 + seg + i * 4];
    union { __bf16 h[4]; unsigned long long u; } ph, pl;
    float sv[4] = {s.x, s.y, s.z, s.w};
#pragma unroll
    for (int q = 0; q < 4; q++) {
      __bf16 hv = (__bf16)sv[q];
      ph.h[q] = hv;
      pl.h[q] = (__bf16)(sv[q] - (float)hv);
    }
    *(unsigned long long*)&Sh[er * 72 + seg + i * 4] = ph.u;
    *(unsigned long long*)&Sl[er * 72 + seg + i * 4] = pl.u;
    float4 qq = *(const float4*)&QeffF[cb + er * 64 + seg + i * 4];
    union { __bf16 h[4]; unsigned long long u; } pq;
    pq.h[0] = (__bf16)qq.x; pq.h[1] = (__bf16)qq.y;
    pq.h[2] = (__bf16)qq.z; pq.h[3] = (__bf16)qq.w;
    *(unsigned long long*)&Qb[er * 72 + seg + i * 4] = pq.u;
  }
  __syncthreads();
  f32x4 acc[4];
#pragma unroll
  for (int ni = 0; ni < 4; ni++) {
    acc[ni] = (f32x4){0.f, 0.f, 0.f, 0.f};
#pragma unroll
    for (int ks = 0; ks < 2; ks++) {
      int aoff = (w * 16 + (lane & 15)) * 72 + ks * 32 + (lane >> 4) * 8;
      int boff = (ni * 16 + (lane & 15)) * 72 + ks * 32 + (lane >> 4) * 8;
      bf16x8 fq = *(const bf16x8*)&Qb[aoff];
      bf16x8 sh = *(const bf16x8*)&Sh[boff];
      bf16x8 sl = *(const bf16x8*)&Sl[boff];
      acc[ni] = __builtin_amdgcn_mfma_f32_16x16x32_bf16(fq, sh, acc[ni], 0, 0, 0);
      acc[ni] = __builtin_amdgcn_mfma_f32_16x16x32_bf16(fq, sl, acc[ni], 0, 0, 0);
    }
  }
  float onwv[4];
#pragma unroll
  for (int ni = 0; ni < 4; ni++) onwv[ni] = onw[ni * 16 + (lane & 15)];
#pragma unroll
  for (int r = 0; r < 4; r++) {
    int t = w * 16 + (lane >> 4) * 4 + r;
    float o[4];
#pragma unroll
    for (int ni = 0; ni < 4; ni++) {
      int e = ni * 16 + (lane & 15);
      o[ni] = obuf[(size_t)bh * 65536 + (size_t)(t0c + t) * 64 + e] + acc[ni][r];
    }
    float ss = o[0] * o[0] + o[1] * o[1] + o[2] * o[2] + o[3] * o[3];
    ss += __shfl_xor(ss, 1);
    ss += __shfl_xor(ss, 2);
    ss += __shfl_xor(ss, 4);
    ss += __shfl_xor(ss, 8);
    float rinv = rsqrtf(ss * (1.f / 64.f) + 1e-6f);
    size_t gbase = ((size_t)(b * 1024 + t0c + t)) * 1024 + h * 64;
#pragma unroll
    for (int ni = 0; ni < 4; ni++) {
      int e = ni * 16 + (lane & 15);
      float on = o[ni] * rinv * onwv[ni];
      float sil = on / (1.f + expf(-on));
      robuf[gbase + e] = g[gbase + e] * sil;
    }
  }
}

// ---------------------------------------------------------------------------
extern "C" void kernel_launch(void* const* d_in, const int* in_sizes, int n_in,
                              void* d_out, int out_size, void* d_ws, size_t ws_size,
                              hipStream_t stream) {
  (void)in_sizes; (void)n_in; (void)out_size; (void)ws_size;
  const float* x    = (const float*)d_in[0];
  const float* Wq   = (const float*)d_in[1];
  const float* Wk   = (const float*)d_in[2];
  const float* Wv   = (const float*)d_in[3];
  const float* Wg   = (const float*)d_in[4];
  const float* Wo   = (const float*)d_in[5];
  const float* bw   = (const float*)d_in[6];
  const float* bb   = (const float*)d_in[7];
  const float* gkw  = (const float*)d_in[8];
  const float* gkb  = (const float*)d_in[9];
  const float* qcw  = (const float*)d_in[10];
  const float* qcb  = (const float*)d_in[11];
  const float* kcw  = (const float*)d_in[12];
  const float* kcb  = (const float*)d_in[13];
  const float* vcw  = (const float*)d_in[14];
  const float* vcb  = (const float*)d_in[15];
  const float* A_log= (const float*)d_in[16];
  const float* Dp   = (const float*)d_in[17];
  const float* dtb  = (const float*)d_in[18];
  const float* onw  = (const float*)d_in[19];

  char* ws = (char*)d_ws;
  const size_t MB = 1024 * 1024;
  // 0..8  : qrb (cra out) -> dead after scanA -> S0TF (scanB out)
  // 8..16 : Wq hi/lo, Wk hi/lo (dead after gemm-proj) -> krb -> robuf (scanCn out)
  // 16..24: Wv hi/lo, Wg hi/lo (dead after gemm-proj) -> vr -> QeffF (self-aliased)
  // 24..28: Wo hi/lo (live to end)
  // 28..36: q_pre -> AcF ; 36..44: k_pre -> BcTF ; 44..52: v_pre -> obuf
  // 52..60: g_buf (live to scanCn) ; 60..61: small buffers
  __bf16* Wq_h = (__bf16*)(ws + 8 * MB);
  __bf16* Wq_l = (__bf16*)(ws + 10 * MB);
  __bf16* Wk_h = (__bf16*)(ws + 12 * MB);
  __bf16* Wk_l = (__bf16*)(ws + 14 * MB);
  __bf16* Wv_h = (__bf16*)(ws + 16 * MB);
  __bf16* Wv_l = (__bf16*)(ws + 18 * MB);
  __bf16* Wg_h = (__bf16*)(ws + 20 * MB);
  __bf16* Wg_l = (__bf16*)(ws + 22 * MB);
  __bf16* Wo_h = (__bf16*)(ws + 24 * MB);
  __bf16* Wo_l = (__bf16*)(ws + 26 * MB);
  float* q_pre = (float*)(ws + 28 * MB);
  float* k_pre = (float*)(ws + 36 * MB);
  float* v_pre = (float*)(ws + 44 * MB);
  float* g_buf = (float*)(ws + 52 * MB);
  float* qrb   = (float*)(ws + 0);
  float* krb   = (float*)(ws + 8 * MB);
  float* vr    = (float*)(ws + 16 * MB);
  float* obuf  = v_pre;
  float* AcF   = (float*)(ws + 28 * MB);
  float* BcTF  = (float*)(ws + 36 * MB);
  float* S0TF  = (float*)(ws + 0);
  float* QeffF = (float*)(ws + 16 * MB);
  float* robuf = (float*)(ws + 8 * MB);
  float* alphaB = (float*)(ws + 60 * MB);
  float* betaB  = (float*)(ws + 60 * MB + 128 * 1024);
  float4* aux   = (float4*)(ws + 60 * MB + 256 * 1024);
  float* gcF    = (float*)(ws + 60 * MB + 768 * 1024);
  float* out    = (float*)d_out;

  k_transp_split<<<dim3(16, 16, 5), 256, 0, stream>>>(
      Wq, Wk, Wv, Wg, Wo,
      Wq_h, Wk_h, Wv_h, Wg_h, Wo_h,
      Wq_l, Wk_l, Wv_l, Wg_l, Wo_l);
  k_gates<<<2048, 256, 0, stream>>>(x, bw, bb, gkw, gkb, A_log, dtb, alphaB, betaB);
  k_gemm3f<<<dim3(8, 16, 4), 256, 0, stream>>>(
      x,
      Wq_h, Wk_h, Wv_h, Wg_h,
      Wq_l, Wk_l, Wv_l, Wg_l,
      q_pre, k_pre, v_pre, g_buf, 1024, 1024);
  k_cra<<<8192, 256, 0, stream>>>(q_pre, k_pre, v_pre,
                                  qcw, qcb, kcw, kcb, vcw, vcb,
                                  alphaB, betaB, Dp, qrb, krb, vr, aux);
  k_scanA<<<512, 128, 0, stream>>>(qrb, krb, vr, aux, obuf, AcF, BcTF, QeffF, gcF);
  k_scanB<<<32, 256, 0, stream>>>(AcF, BcTF, gcF, S0TF);
  k_scanCn<<<512, 256, 0, stream>>>(S0TF, QeffF, obuf, g_buf, onw, robuf);
  k_gemm3f<<<dim3(8, 16, 1), 256, 0, stream>>>(
      robuf,
      Wo_h, Wo_h, Wo_h, Wo_h,
      Wo_l, Wo_l, Wo_l, Wo_l,
      out, out, out, out, 1024, 1024);
}